// Round 1
// baseline (1193.956 us; speedup 1.0000x reference)
//
#include <hip/hip_runtime.h>

// M02SameVQ: VQ nearest-centroid + residual MLP autoencoder, MI355X (gfx950).
//
// Pipeline:
//  1. conv_centroid: centroid f32 -> c_hi/c_lo bf16 + c_norm f32
//  2. conv_feature : feature (B,C,T) f32 -> x_hi/x_lo bf16 (B*T, C)  [LDS transpose]
//  3. f2bf x6      : MLP weights f32 -> bf16
//  4. gemm<3,SCORE>: s = x_hi.c_hi + x_lo.c_hi + x_hi.c_lo - 0.5*c_norm, per-row
//                    partial argmax written per 64-col chunk
//  5. argmax_reduce: 64 chunks -> idx[row]
//  6. build_spk    : spk = (x_hi+x_lo) - centroid[idx]  (bf16)
//  7. gemm<1,STORE> x6: MLP layers (bias + leaky-relu fused)
//  8. transpose_out: out[b,c,t] = centroid[idx] + spk_dec  [LDS transpose]
//
// GEMM = m97 structure: 128x128 tile, BK=64, 4 waves 2x2, global_load_lds w=16
// with pre-swizzled source + XOR-swizzled ds_read_b128 (swizzle both sides).
// ws usage ~230 MB.

typedef unsigned short u16;
typedef unsigned int   u32;
typedef __bf16 bf16x8 __attribute__((ext_vector_type(8)));
typedef float  f32x4  __attribute__((ext_vector_type(4)));

#define AS1 __attribute__((address_space(1)))
#define AS3 __attribute__((address_space(3)))

__device__ __forceinline__ u16 rne_bf16(float f) {
  u32 u = __float_as_uint(f);
  u = (u + 0x7FFFu + ((u >> 16) & 1u)) >> 16;
  return (u16)u;
}
__device__ __forceinline__ float b2f(u16 h) {
  return __uint_as_float(((u32)h) << 16);
}

// ---------------------------------------------------------------- conversions

// centroid (NBIN x C) f32 -> hi/lo bf16 + row squared norm. One wave per row.
__global__ __launch_bounds__(256) void conv_centroid(
    const float* __restrict__ cent, u16* __restrict__ chi, u16* __restrict__ clo,
    float* __restrict__ cnorm, int K)
{
  int row  = blockIdx.x * 4 + (threadIdx.x >> 6);
  int lane = threadIdx.x & 63;
  const float* cr = cent + (size_t)row * K;
  float s = 0.f;
  for (int j = 0; j < K; j += 64) {
    int k = j + lane;
    float f = cr[k];
    s += f * f;
    u32 u = __float_as_uint(f);
    u32 hi = (u + 0x7FFFu + ((u >> 16) & 1u)) >> 16;
    float fhi = __uint_as_float(hi << 16);
    chi[(size_t)row * K + k] = (u16)hi;
    clo[(size_t)row * K + k] = rne_bf16(f - fhi);
  }
#pragma unroll
  for (int m = 1; m < 64; m <<= 1) s += __shfl_xor(s, m, 64);
  if (lane == 0) cnorm[row] = s;
}

// feature (B,C,T) f32 -> x_hi/x_lo bf16 laid out (B*T, C). 64x64 LDS transpose.
__global__ __launch_bounds__(256) void conv_feature(
    const float* __restrict__ feat, u16* __restrict__ xhi, u16* __restrict__ xlo,
    int C, int T)
{
  __shared__ float tile[64][65];
  int bb = blockIdx.z, c0 = blockIdx.y * 64, t0 = blockIdx.x * 64;
  const float* fb = feat + (size_t)bb * C * T;
#pragma unroll
  for (int i = 0; i < 16; ++i) {
    int id = threadIdx.x + i * 256;
    int lc = id >> 6, lt = id & 63;              // lanes vary lt -> coalesced read
    int t = t0 + lt;
    tile[lc][lt] = (t < T) ? fb[(size_t)(c0 + lc) * T + t] : 0.f;
  }
  __syncthreads();
#pragma unroll
  for (int i = 0; i < 16; ++i) {
    int id = threadIdx.x + i * 256;
    int lt = id >> 6, lc = id & 63;              // lanes vary lc -> coalesced write
    int t = t0 + lt;
    if (t < T) {
      size_t row = (size_t)bb * T + t;
      float f = tile[lc][lt];
      u32 u = __float_as_uint(f);
      u32 hi = (u + 0x7FFFu + ((u >> 16) & 1u)) >> 16;
      float fhi = __uint_as_float(hi << 16);
      xhi[row * C + c0 + lc] = (u16)hi;
      xlo[row * C + c0 + lc] = rne_bf16(f - fhi);
    }
  }
}

__global__ __launch_bounds__(256) void f2bf(
    const float* __restrict__ s, u16* __restrict__ d, int n)
{
  int i = blockIdx.x * 256 + threadIdx.x;
  if (i < n) d[i] = rne_bf16(s[i]);
}

// ---------------------------------------------------------------------- GEMM
// C[M][N] = sum_seg A_seg (MxK, row-major bf16) . B_seg (NxK, row-major bf16)^T
// SCORE epilogue: per-row argmax of (acc - 0.5*c_norm[col]) over this block's
//   64-col wave span -> pval/pidx[row][chunk]
// STORE epilogue: bf16( act(acc + bias[col]) ) -> outb[row][col]
template<int NSEG, bool SCORE, bool ACT>
__global__ __launch_bounds__(256) void gemm_bt(
    const u16* __restrict__ A0, const u16* __restrict__ A1, const u16* __restrict__ A2,
    const u16* __restrict__ B0, const u16* __restrict__ B1, const u16* __restrict__ B2,
    const float* __restrict__ cnb,          // SCORE: c_norm[N], STORE: bias[N]
    u16* __restrict__ outb,
    float* __restrict__ pval, int* __restrict__ pidx,
    int M, int N, int K)
{
  __shared__ bf16x8 smem8[2048];            // 32 KiB: A [0,16K), B [16K,32K)
  char* smem = (char*)smem8;

  const int lane = threadIdx.x & 63;
  const int wid  = threadIdx.x >> 6;
  const int wm   = wid >> 1, wn = wid & 1;

  const int rowBase = blockIdx.y * 128;
  const int colBase = blockIdx.x * 128;

  const f32x4 zero4 = {0.f, 0.f, 0.f, 0.f};
  f32x4 acc[4][4];
#pragma unroll
  for (int i = 0; i < 4; ++i)
#pragma unroll
    for (int j = 0; j < 4; ++j) acc[i][j] = zero4;

  const int l8   = lane >> 3;                    // 0..7 (row within 8-row chunk)
  const int kbsw = ((lane & 7) ^ l8) << 4;       // swizzled source byte offset
  const int kseg = K >> 6;
  const int nkt  = NSEG * kseg;

  for (int kt = 0; kt < nkt; ++kt) {
    int seg, k0;
    if (NSEG == 1) { seg = 0; k0 = kt << 6; }
    else           { seg = kt / kseg; k0 = (kt - seg * kseg) << 6; }
    const u16* Aseg = (seg == 0) ? A0 : (seg == 1 ? A1 : A2);
    const u16* Bseg = (seg == 0) ? B0 : (seg == 1 ? B1 : B2);

#pragma unroll
    for (int i = 0; i < 4; ++i) {
      int c = wid * 4 + i;                       // 1 KiB LDS chunk id (0..15)
      int r = c * 8 + l8;                        // tile row 0..127
      int gra = rowBase + r; gra = gra < M ? gra : (M - 1);   // clamp M edge
      const char* ga = (const char*)Aseg + ((size_t)gra * K + k0) * 2 + kbsw;
      __builtin_amdgcn_global_load_lds((const AS1 void*)ga,
                                       (AS3 void*)(smem + c * 1024), 16, 0, 0);
      int grb = colBase + r;                     // N is multiple of 128
      const char* gb = (const char*)Bseg + ((size_t)grb * K + k0) * 2 + kbsw;
      __builtin_amdgcn_global_load_lds((const AS1 void*)gb,
                                       (AS3 void*)(smem + 16384 + c * 1024), 16, 0, 0);
    }
    __syncthreads();

#pragma unroll
    for (int kk = 0; kk < 64; kk += 32) {
      bf16x8 a[4], b[4];
      const int kb = (kk + ((lane >> 4) << 3)) << 1;
#pragma unroll
      for (int mf = 0; mf < 4; ++mf) {
        int row = wm * 64 + mf * 16 + (lane & 15);
        a[mf] = *(const bf16x8*)(smem + row * 128 + (kb ^ ((row & 7) << 4)));
      }
#pragma unroll
      for (int nf = 0; nf < 4; ++nf) {
        int row = wn * 64 + nf * 16 + (lane & 15);
        b[nf] = *(const bf16x8*)(smem + 16384 + row * 128 + (kb ^ ((row & 7) << 4)));
      }
#pragma unroll
      for (int mf = 0; mf < 4; ++mf)
#pragma unroll
        for (int nf = 0; nf < 4; ++nf)
          acc[mf][nf] = __builtin_amdgcn_mfma_f32_16x16x32_bf16(
              a[mf], b[nf], acc[mf][nf], 0, 0, 0);
    }
    __syncthreads();
  }

  // D layout (m89-verified): col = lane&15, row = (lane>>4)*4 + reg
  const int colLane = colBase + wn * 64 + (lane & 15);

  if (SCORE) {
    float cn[4];
#pragma unroll
    for (int nf = 0; nf < 4; ++nf) cn[nf] = 0.5f * cnb[colLane + nf * 16];
    const int nchunk = N >> 6;
    const int chunk  = (colBase >> 6) + wn;
#pragma unroll
    for (int mf = 0; mf < 4; ++mf) {
#pragma unroll
      for (int reg = 0; reg < 4; ++reg) {
        float best = acc[mf][0][reg] - cn[0];
        int   bc   = colLane;
#pragma unroll
        for (int nf = 1; nf < 4; ++nf) {
          float v = acc[mf][nf][reg] - cn[nf];
          int c2 = colLane + nf * 16;
          if (v > best || (v == best && c2 < bc)) { best = v; bc = c2; }
        }
#pragma unroll
        for (int m = 1; m < 16; m <<= 1) {       // reduce across lane bits 0..3
          float vo = __shfl_xor(best, m, 64);
          int   co = __shfl_xor(bc,   m, 64);
          if (vo > best || (vo == best && co < bc)) { best = vo; bc = co; }
        }
        if ((lane & 15) == 0) {
          int row = rowBase + wm * 64 + mf * 16 + ((lane >> 4) << 2) + reg;
          if (row < M) {
            pval[(size_t)row * nchunk + chunk] = best;
            pidx[(size_t)row * nchunk + chunk] = bc;
          }
        }
      }
    }
  } else {
    float bl[4];
#pragma unroll
    for (int nf = 0; nf < 4; ++nf) bl[nf] = cnb[colLane + nf * 16];
#pragma unroll
    for (int mf = 0; mf < 4; ++mf)
#pragma unroll
      for (int nf = 0; nf < 4; ++nf)
#pragma unroll
        for (int reg = 0; reg < 4; ++reg) {
          int row = rowBase + wm * 64 + mf * 16 + ((lane >> 4) << 2) + reg;
          if (row < M) {
            float v = acc[mf][nf][reg] + bl[nf];
            if (ACT) v = v > 0.f ? v : 0.01f * v;
            outb[(size_t)row * N + colLane + nf * 16] = rne_bf16(v);
          }
        }
  }
}

// -------------------------------------------------------------- small kernels

__global__ __launch_bounds__(256) void argmax_reduce(
    const float* __restrict__ pval, const int* __restrict__ pidx,
    int* __restrict__ idxOut, int nchunk)
{
  int row  = blockIdx.x * 4 + (threadIdx.x >> 6);
  int lane = threadIdx.x & 63;
  float v = pval[(size_t)row * nchunk + lane];
  int   c = pidx[(size_t)row * nchunk + lane];
#pragma unroll
  for (int m = 1; m < 64; m <<= 1) {
    float vo = __shfl_xor(v, m, 64);
    int   co = __shfl_xor(c, m, 64);
    if (vo > v || (vo == v && co < c)) { v = vo; c = co; }
  }
  if (lane == 0) idxOut[row] = c;
}

__global__ __launch_bounds__(256) void build_spk(
    const u16* __restrict__ xhi, const u16* __restrict__ xlo,
    const float* __restrict__ cent, const int* __restrict__ idx,
    u16* __restrict__ spk, int C)
{
  int row = blockIdx.x;
  const float* cr = cent + (size_t)idx[row] * C;
  size_t base = (size_t)row * C;
  for (int c = threadIdx.x; c < C; c += 256) {
    float v = b2f(xhi[base + c]) + b2f(xlo[base + c]) - cr[c];
    spk[base + c] = rne_bf16(v);
  }
}

// out[b,c,t] = centroid[idx[row]][c] + spk_dec[row][c],  row = b*T+t.
__global__ __launch_bounds__(256) void transpose_out(
    const u16* __restrict__ spkdec, const float* __restrict__ cent,
    const int* __restrict__ idx, float* __restrict__ out, int C, int T)
{
  __shared__ float tile[64][65];
  int r0 = blockIdx.x * 64, c0 = blockIdx.y * 64;
#pragma unroll
  for (int i = 0; i < 16; ++i) {
    int id = threadIdx.x + i * 256;
    int lr = id >> 6, lc = id & 63;              // lanes vary lc -> coalesced
    int row = r0 + lr;
    tile[lr][lc] = b2f(spkdec[(size_t)row * C + c0 + lc])
                 + cent[(size_t)idx[row] * C + c0 + lc];
  }
  __syncthreads();
#pragma unroll
  for (int i = 0; i < 16; ++i) {
    int id = threadIdx.x + i * 256;
    int lc = id >> 6, lr = id & 63;              // lanes vary lr (=t) -> coalesced
    int row = r0 + lr;
    int b = row / T, t = row - b * T;
    out[((size_t)b * C + c0 + lc) * T + t] = tile[lr][lc];
  }
}

// --------------------------------------------------------------------- launch

extern "C" void kernel_launch(void* const* d_in, const int* in_sizes, int n_in,
                              void* d_out, int out_size, void* d_ws, size_t ws_size,
                              hipStream_t stream)
{
  const float* feature  = (const float*)d_in[0];
  const float* centroid = (const float*)d_in[1];
  const float* ew0 = (const float*)d_in[2];
  const float* eb0 = (const float*)d_in[3];
  const float* ew1 = (const float*)d_in[4];
  const float* eb1 = (const float*)d_in[5];
  const float* ew2 = (const float*)d_in[6];
  const float* eb2 = (const float*)d_in[7];
  const float* dw0 = (const float*)d_in[8];
  const float* db0 = (const float*)d_in[9];
  const float* dw1 = (const float*)d_in[10];
  const float* db1 = (const float*)d_in[11];
  const float* dw2 = (const float*)d_in[12];
  const float* db2 = (const float*)d_in[13];
  float* out = (float*)d_out;

  const int Bb = 16, C = 1024, T = 1500, M = Bb * T;    // M = 24000
  const int NBIN = 4096, HID = 512, EMB = 256;
  const int MB = (M + 127) / 128;                       // 188 row-blocks

  char* ws = (char*)d_ws;
  size_t off = 0;
  auto alloc = [&](size_t bytes) -> char* {
    char* p = ws + off;
    off += (bytes + 255) & ~(size_t)255;
    return p;
  };
  u16*   c_hi  = (u16*)  alloc((size_t)NBIN * C * 2);
  u16*   c_lo  = (u16*)  alloc((size_t)NBIN * C * 2);
  float* cnorm = (float*)alloc((size_t)NBIN * 4);
  u16*   wb0   = (u16*)  alloc((size_t)HID * C   * 2);
  u16*   wb1   = (u16*)  alloc((size_t)HID * HID * 2);
  u16*   wb2   = (u16*)  alloc((size_t)EMB * HID * 2);
  u16*   wb3   = (u16*)  alloc((size_t)HID * EMB * 2);
  u16*   wb4   = (u16*)  alloc((size_t)HID * HID * 2);
  u16*   wb5   = (u16*)  alloc((size_t)C   * HID * 2);
  u16*   x_hi  = (u16*)  alloc((size_t)M * C * 2);
  u16*   x_lo  = (u16*)  alloc((size_t)M * C * 2);
  int*   idx   = (int*)  alloc((size_t)M * 4);
  char*  spkR  =         alloc((size_t)M * C * 2);      // spk, later spk_dec
  u16*   spk   = (u16*)spkR;
  float* pval  = (float*)spkR;                          // overlay (pre-spk)
  int*   pidx  = (int*)(spkR + (size_t)M * 64 * 4);     // overlay (pre-spk)
  u16*   h1    = (u16*)  alloc((size_t)M * HID * 2);
  u16*   h2    = (u16*)  alloc((size_t)M * HID * 2);
  u16*   hz    = (u16*)  alloc((size_t)M * EMB * 2);
  // total ~230 MB

  // 1-3: conversions
  conv_centroid<<<NBIN / 4, 256, 0, stream>>>(centroid, c_hi, c_lo, cnorm, C);
  conv_feature<<<dim3((T + 63) / 64, C / 64, Bb), 256, 0, stream>>>(feature, x_hi, x_lo, C, T);
  f2bf<<<(HID * C   + 255) / 256, 256, 0, stream>>>(ew0, wb0, HID * C);
  f2bf<<<(HID * HID + 255) / 256, 256, 0, stream>>>(ew1, wb1, HID * HID);
  f2bf<<<(EMB * HID + 255) / 256, 256, 0, stream>>>(ew2, wb2, EMB * HID);
  f2bf<<<(HID * EMB + 255) / 256, 256, 0, stream>>>(dw0, wb3, HID * EMB);
  f2bf<<<(HID * HID + 255) / 256, 256, 0, stream>>>(dw1, wb4, HID * HID);
  f2bf<<<(C   * HID + 255) / 256, 256, 0, stream>>>(dw2, wb5, C * HID);

  // 4: score GEMM (hi.hi + lo.hi + hi.lo) with fused partial argmax
  gemm_bt<3, true, false><<<dim3(NBIN / 128, MB), 256, 0, stream>>>(
      x_hi, x_lo, x_hi, c_hi, c_hi, c_lo, cnorm, nullptr, pval, pidx, M, NBIN, C);

  // 5: final argmax
  argmax_reduce<<<M / 4, 256, 0, stream>>>(pval, pidx, idx, NBIN / 64);

  // 6: residual (overwrites pval/pidx overlay region)
  build_spk<<<M, 256, 0, stream>>>(x_hi, x_lo, centroid, idx, spk, C);

  // 7: MLP encoder/decoder
  gemm_bt<1, false, true ><<<dim3(HID / 128, MB), 256, 0, stream>>>(
      spk, spk, spk, wb0, wb0, wb0, eb0, h1, nullptr, nullptr, M, HID, C);
  gemm_bt<1, false, true ><<<dim3(HID / 128, MB), 256, 0, stream>>>(
      h1, h1, h1, wb1, wb1, wb1, eb1, h2, nullptr, nullptr, M, HID, HID);
  gemm_bt<1, false, false><<<dim3(EMB / 128, MB), 256, 0, stream>>>(
      h2, h2, h2, wb2, wb2, wb2, eb2, hz, nullptr, nullptr, M, EMB, HID);
  gemm_bt<1, false, true ><<<dim3(HID / 128, MB), 256, 0, stream>>>(
      hz, hz, hz, wb3, wb3, wb3, db0, h1, nullptr, nullptr, M, HID, EMB);
  gemm_bt<1, false, true ><<<dim3(HID / 128, MB), 256, 0, stream>>>(
      h1, h1, h1, wb4, wb4, wb4, db1, h2, nullptr, nullptr, M, HID, HID);
  gemm_bt<1, false, false><<<dim3(C / 128, MB), 256, 0, stream>>>(
      h2, h2, h2, wb5, wb5, wb5, db2, spk, nullptr, nullptr, M, C, HID);

  // 8: merge + transpose to (B,C,T)
  transpose_out<<<dim3(M / 64, C / 64), 256, 0, stream>>>(spk, centroid, idx, out, C, T);
}

// Round 2
// 1086.262 us; speedup vs baseline: 1.0991x; 1.0991x over previous
//
#include <hip/hip_runtime.h>

// M02SameVQ: VQ nearest-centroid + residual MLP autoencoder, MI355X (gfx950).
//
// Round 2: score GEMM moved to the 256^2 8-phase template (T3+T4+T5):
//   - 256x256 tile, BK=64, 8 waves (2M x 4N), 512 threads, 128 KiB LDS dbuf
//   - raw s_barrier + counted s_waitcnt vmcnt(4) at phases 4/8 only
//   - setprio(1) around MFMA clusters
//   - (row&7)<<4 XOR swizzle, pre-swizzled global_load_lds source (rule #21)
// Schedule (tiles t=2i in buf0, t+1 in buf1; halves A0,A1,B0,B1; 2 loads/half):
//   ph1: rd a03,b01(buf0); stage B0(t+1)   ph5: rd a03,b01(buf1); stage B0(t+2)
//   ph2: rd b23,a47(buf0); stage B1(t+1)   ph6: rd b23,a47(buf1); stage B1(t+2)
//   ph3: stage A0(t+2)                     ph7: stage A0(t+3)
//   ph4: stage A1(t+2) [vmcnt(4)]          ph8: stage A1(t+3) [vmcnt(4)]
// Overwrite safety: a buffer's ds_reads all complete (into regs, barrier-
// ordered) before any stage targeting it is issued. vmcnt(4) = 2 halves in
// flight ensures consumed halves have landed before the next compute phase.
// MLP GEMMs keep the round-1 128^2 m97 structure.

typedef unsigned short u16;
typedef unsigned int   u32;
typedef __bf16 bf16x8 __attribute__((ext_vector_type(8)));
typedef float  f32x4  __attribute__((ext_vector_type(4)));

#define AS1 __attribute__((address_space(1)))
#define AS3 __attribute__((address_space(3)))

__device__ __forceinline__ u16 rne_bf16(float f) {
  u32 u = __float_as_uint(f);
  u = (u + 0x7FFFu + ((u >> 16) & 1u)) >> 16;
  return (u16)u;
}
__device__ __forceinline__ float b2f(u16 h) {
  return __uint_as_float(((u32)h) << 16);
}

// ---------------------------------------------------------------- conversions

__global__ __launch_bounds__(256) void conv_centroid(
    const float* __restrict__ cent, u16* __restrict__ chi, u16* __restrict__ clo,
    float* __restrict__ cnorm, int K)
{
  int row  = blockIdx.x * 4 + (threadIdx.x >> 6);
  int lane = threadIdx.x & 63;
  const float* cr = cent + (size_t)row * K;
  float s = 0.f;
  for (int j = 0; j < K; j += 64) {
    int k = j + lane;
    float f = cr[k];
    s += f * f;
    u32 u = __float_as_uint(f);
    u32 hi = (u + 0x7FFFu + ((u >> 16) & 1u)) >> 16;
    float fhi = __uint_as_float(hi << 16);
    chi[(size_t)row * K + k] = (u16)hi;
    clo[(size_t)row * K + k] = rne_bf16(f - fhi);
  }
#pragma unroll
  for (int m = 1; m < 64; m <<= 1) s += __shfl_xor(s, m, 64);
  if (lane == 0) cnorm[row] = s;
}

__global__ __launch_bounds__(256) void conv_feature(
    const float* __restrict__ feat, u16* __restrict__ xhi, u16* __restrict__ xlo,
    int C, int T)
{
  __shared__ float tile[64][65];
  int bb = blockIdx.z, c0 = blockIdx.y * 64, t0 = blockIdx.x * 64;
  const float* fb = feat + (size_t)bb * C * T;
#pragma unroll
  for (int i = 0; i < 16; ++i) {
    int id = threadIdx.x + i * 256;
    int lc = id >> 6, lt = id & 63;
    int t = t0 + lt;
    tile[lc][lt] = (t < T) ? fb[(size_t)(c0 + lc) * T + t] : 0.f;
  }
  __syncthreads();
#pragma unroll
  for (int i = 0; i < 16; ++i) {
    int id = threadIdx.x + i * 256;
    int lt = id >> 6, lc = id & 63;
    int t = t0 + lt;
    if (t < T) {
      size_t row = (size_t)bb * T + t;
      float f = tile[lc][lt];
      u32 u = __float_as_uint(f);
      u32 hi = (u + 0x7FFFu + ((u >> 16) & 1u)) >> 16;
      float fhi = __uint_as_float(hi << 16);
      xhi[row * C + c0 + lc] = (u16)hi;
      xlo[row * C + c0 + lc] = rne_bf16(f - fhi);
    }
  }
}

__global__ __launch_bounds__(256) void f2bf(
    const float* __restrict__ s, u16* __restrict__ d, int n)
{
  int i = blockIdx.x * 256 + threadIdx.x;
  if (i < n) d[i] = rne_bf16(s[i]);
}

// ----------------------------------------------------- 256^2 8-phase score GEMM

template<int KK, int NSEG>
__global__ __launch_bounds__(512, 2) void score256(
    const u16* __restrict__ A0, const u16* __restrict__ A1, const u16* __restrict__ A2,
    const u16* __restrict__ B0s, const u16* __restrict__ B1s, const u16* __restrict__ B2s,
    const float* __restrict__ cnb, float* __restrict__ pval, int* __restrict__ pidx,
    int M, int N)
{
  constexpr int NKTPS = KK / 64;
  constexpr int NKT   = NSEG * NKTPS;
  static_assert(NKT % 2 == 0, "even tile count");

  __shared__ f32x4 smem4[8192];             // 128 KiB
  char* smem = (char*)smem4;
  // layout: A buf0 [0,32K) | A buf1 [32K,64K) | B buf0 [64K,96K) | B buf1 [96K,128K)

  const int lane = threadIdx.x & 63;
  const int wid  = threadIdx.x >> 6;        // 0..7
  const int wr   = wid >> 2;                // 0..1 (M)
  const int wc   = wid & 3;                 // 0..3 (N)

  const int rowBase = blockIdx.y * 256;
  const int colBase = blockIdx.x * 256;

  const int kswz  = ((lane & 7) ^ (lane >> 3)) << 4;  // pre-swizzled source k
  const int kbase = (lane >> 4) << 4;                 // frag k-byte 0/16/32/48

  const f32x4 zero4 = {0.f, 0.f, 0.f, 0.f};
  f32x4 acc[8][4];
#pragma unroll
  for (int i = 0; i < 8; ++i)
#pragma unroll
    for (int j = 0; j < 4; ++j) acc[i][j] = zero4;

  bf16x8 aR[2][4][2];   // [qm][mf][kh]
  bf16x8 bR[2][2][2];   // [qn][nf][kh]

  // ---- staging: half h (0/1) of tile t into buffer b. 2 loads/wave.
  auto stage = [&](int b, int isB, int h, int t) {
    int tc  = t < NKT ? t : NKT - 1;
    int seg = tc / NKTPS;
    int k0  = (tc - seg * NKTPS) << 6;
    const u16* S = isB ? (seg == 0 ? B0s : (seg == 1 ? B1s : B2s))
                       : (seg == 0 ? A0  : (seg == 1 ? A1  : A2));
    int rcBase = isB ? colBase : rowBase;
    char* dst = smem + (isB ? 65536 : 0) + b * 32768 + h * 16384 + wid * 1024;
#pragma unroll
    for (int j = 0; j < 2; ++j) {
      int r  = h * 128 + j * 64 + wid * 8 + (lane >> 3);
      int gr = rcBase + r;
      if (!isB) gr = gr < M ? gr : M - 1;   // clamp A rows at M edge
      const char* ga = (const char*)S + ((size_t)gr * KK + k0) * 2 + kswz;
      __builtin_amdgcn_global_load_lds((const AS1 void*)ga,
                                       (AS3 void*)(dst + j * 8192), 16, 0, 0);
    }
  };

#define LDA_H(b, qm) do { \
  _Pragma("unroll") for (int mf = 0; mf < 4; ++mf) { \
    int row = wr * 128 + (qm) * 64 + mf * 16 + (lane & 15); \
    const char* p = smem + (b) * 32768 + row * 128; \
    int sw = (row & 7) << 4; \
    aR[qm][mf][0] = *(const bf16x8*)(p + (kbase ^ sw)); \
    aR[qm][mf][1] = *(const bf16x8*)(p + ((kbase + 64) ^ sw)); \
  } } while (0)

#define LDB_H(b, qn) do { \
  _Pragma("unroll") for (int nf = 0; nf < 2; ++nf) { \
    int row = wc * 64 + (qn) * 32 + nf * 16 + (lane & 15); \
    const char* p = smem + 65536 + (b) * 32768 + row * 128; \
    int sw = (row & 7) << 4; \
    bR[qn][nf][0] = *(const bf16x8*)(p + (kbase ^ sw)); \
    bR[qn][nf][1] = *(const bf16x8*)(p + ((kbase + 64) ^ sw)); \
  } } while (0)

#define MMQ(qm, qn) do { \
  _Pragma("unroll") for (int mf = 0; mf < 4; ++mf) \
  _Pragma("unroll") for (int nf = 0; nf < 2; ++nf) { \
    acc[(qm)*4+mf][(qn)*2+nf] = __builtin_amdgcn_mfma_f32_16x16x32_bf16( \
        aR[qm][mf][0], bR[qn][nf][0], acc[(qm)*4+mf][(qn)*2+nf], 0, 0, 0); \
    acc[(qm)*4+mf][(qn)*2+nf] = __builtin_amdgcn_mfma_f32_16x16x32_bf16( \
        aR[qm][mf][1], bR[qn][nf][1], acc[(qm)*4+mf][(qn)*2+nf], 0, 0, 0); \
  } } while (0)

#define BAR()    __builtin_amdgcn_s_barrier()
#define PRIO1()  __builtin_amdgcn_s_setprio(1)
#define PRIO0()  __builtin_amdgcn_s_setprio(0)
#define VMCNT4() asm volatile("s_waitcnt vmcnt(4)" ::: "memory")

  // ---- prologue: tile0 all 4 halves + tile1 A-halves, then wait tile0.
  stage(0, 0, 0, 0); stage(0, 0, 1, 0); stage(0, 1, 0, 0); stage(0, 1, 1, 0);
  stage(1, 0, 0, 1); stage(1, 0, 1, 1);
  VMCNT4();
  BAR();

  // ---- main loop: 2 K-tiles (8 phases) per iteration.
  for (int i = 0; i < NKT / 2; ++i) {
    const int t = 2 * i;
    // ph1: tile t (buf0) quadrant (0,0)
    LDA_H(0, 0); LDB_H(0, 0);
    stage(1, 1, 0, t + 1);
    BAR(); PRIO1(); MMQ(0, 0); PRIO0(); BAR();
    // ph2: quadrant (0,1)
    LDB_H(0, 1); LDA_H(0, 1);
    stage(1, 1, 1, t + 1);
    BAR(); PRIO1(); MMQ(0, 1); PRIO0(); BAR();
    // ph3: quadrant (1,1)
    stage(0, 0, 0, t + 2);
    BAR(); PRIO1(); MMQ(1, 1); PRIO0(); BAR();
    // ph4: quadrant (1,0), wait for t+1's B halves
    stage(0, 0, 1, t + 2);
    BAR(); PRIO1(); MMQ(1, 0); PRIO0(); VMCNT4(); BAR();
    // ph5: tile t+1 (buf1) quadrant (0,0)
    LDA_H(1, 0); LDB_H(1, 0);
    stage(0, 1, 0, t + 2);
    BAR(); PRIO1(); MMQ(0, 0); PRIO0(); BAR();
    // ph6: quadrant (0,1)
    LDB_H(1, 1); LDA_H(1, 1);
    stage(0, 1, 1, t + 2);
    BAR(); PRIO1(); MMQ(0, 1); PRIO0(); BAR();
    // ph7: quadrant (1,1)
    stage(1, 0, 0, t + 3);
    BAR(); PRIO1(); MMQ(1, 1); PRIO0(); BAR();
    // ph8: quadrant (1,0), wait for t+2's B halves
    stage(1, 0, 1, t + 3);
    BAR(); PRIO1(); MMQ(1, 0); PRIO0(); VMCNT4(); BAR();
  }

  // ---- epilogue: fused partial argmax of (acc - 0.5*c_norm) per 64-col chunk.
  const int colL = colBase + wc * 64 + (lane & 15);
  float cn[4];
#pragma unroll
  for (int ni = 0; ni < 4; ++ni) cn[ni] = 0.5f * cnb[colL + ni * 16];
  const int nchunk = N >> 6;
  const int chunk  = (colBase >> 6) + wc;
#pragma unroll
  for (int mi = 0; mi < 8; ++mi) {
#pragma unroll
    for (int reg = 0; reg < 4; ++reg) {
      float best = acc[mi][0][reg] - cn[0];
      int   bc   = colL;
#pragma unroll
      for (int ni = 1; ni < 4; ++ni) {
        float v  = acc[mi][ni][reg] - cn[ni];
        int   c2 = colL + ni * 16;
        if (v > best || (v == best && c2 < bc)) { best = v; bc = c2; }
      }
#pragma unroll
      for (int m = 1; m < 16; m <<= 1) {
        float vo = __shfl_xor(best, m, 64);
        int   co = __shfl_xor(bc,   m, 64);
        if (vo > best || (vo == best && co < bc)) { best = vo; bc = co; }
      }
      if ((lane & 15) == 0) {
        int row = rowBase + wr * 128 + (mi >> 2) * 64 + (mi & 3) * 16
                + ((lane >> 4) << 2) + reg;
        if (row < M) {
          pval[(size_t)row * nchunk + chunk] = best;
          pidx[(size_t)row * nchunk + chunk] = bc;
        }
      }
    }
  }
#undef LDA_H
#undef LDB_H
#undef MMQ
#undef BAR
#undef PRIO1
#undef PRIO0
#undef VMCNT4
}

// ------------------------------------------------- 128^2 GEMM (MLP layers)

template<int NSEG, bool SCORE, bool ACT>
__global__ __launch_bounds__(256) void gemm_bt(
    const u16* __restrict__ A0, const u16* __restrict__ A1, const u16* __restrict__ A2,
    const u16* __restrict__ B0, const u16* __restrict__ B1, const u16* __restrict__ B2,
    const float* __restrict__ cnb, u16* __restrict__ outb,
    float* __restrict__ pval, int* __restrict__ pidx,
    int M, int N, int K)
{
  __shared__ bf16x8 smem8[2048];            // 32 KiB: A [0,16K), B [16K,32K)
  char* smem = (char*)smem8;

  const int lane = threadIdx.x & 63;
  const int wid  = threadIdx.x >> 6;
  const int wm   = wid >> 1, wn = wid & 1;

  const int rowBase = blockIdx.y * 128;
  const int colBase = blockIdx.x * 128;

  const f32x4 zero4 = {0.f, 0.f, 0.f, 0.f};
  f32x4 acc[4][4];
#pragma unroll
  for (int i = 0; i < 4; ++i)
#pragma unroll
    for (int j = 0; j < 4; ++j) acc[i][j] = zero4;

  const int l8   = lane >> 3;
  const int kbsw = ((lane & 7) ^ l8) << 4;
  const int kseg = K >> 6;
  const int nkt  = NSEG * kseg;

  for (int kt = 0; kt < nkt; ++kt) {
    int seg, k0;
    if (NSEG == 1) { seg = 0; k0 = kt << 6; }
    else           { seg = kt / kseg; k0 = (kt - seg * kseg) << 6; }
    const u16* Aseg = (seg == 0) ? A0 : (seg == 1 ? A1 : A2);
    const u16* Bseg = (seg == 0) ? B0 : (seg == 1 ? B1 : B2);

#pragma unroll
    for (int i = 0; i < 4; ++i) {
      int c = wid * 4 + i;
      int r = c * 8 + l8;
      int gra = rowBase + r; gra = gra < M ? gra : (M - 1);
      const char* ga = (const char*)Aseg + ((size_t)gra * K + k0) * 2 + kbsw;
      __builtin_amdgcn_global_load_lds((const AS1 void*)ga,
                                       (AS3 void*)(smem + c * 1024), 16, 0, 0);
      int grb = colBase + r;
      const char* gb = (const char*)Bseg + ((size_t)grb * K + k0) * 2 + kbsw;
      __builtin_amdgcn_global_load_lds((const AS1 void*)gb,
                                       (AS3 void*)(smem + 16384 + c * 1024), 16, 0, 0);
    }
    __syncthreads();

#pragma unroll
    for (int kk = 0; kk < 64; kk += 32) {
      bf16x8 a[4], b[4];
      const int kb = (kk + ((lane >> 4) << 3)) << 1;
#pragma unroll
      for (int mf = 0; mf < 4; ++mf) {
        int row = wm * 64 + mf * 16 + (lane & 15);
        a[mf] = *(const bf16x8*)(smem + row * 128 + (kb ^ ((row & 7) << 4)));
      }
#pragma unroll
      for (int nf = 0; nf < 4; ++nf) {
        int row = wn * 64 + nf * 16 + (lane & 15);
        b[nf] = *(const bf16x8*)(smem + 16384 + row * 128 + (kb ^ ((row & 7) << 4)));
      }
#pragma unroll
      for (int mf = 0; mf < 4; ++mf)
#pragma unroll
        for (int nf = 0; nf < 4; ++nf)
          acc[mf][nf] = __builtin_amdgcn_mfma_f32_16x16x32_bf16(
              a[mf], b[nf], acc[mf][nf], 0, 0, 0);
    }
    __syncthreads();
  }

  const int colLane = colBase + wn * 64 + (lane & 15);

  if (SCORE) {
    float cn[4];
#pragma unroll
    for (int nf = 0; nf < 4; ++nf) cn[nf] = 0.5f * cnb[colLane + nf * 16];
    const int nchunk = N >> 6;
    const int chunk  = (colBase >> 6) + wn;
#pragma unroll
    for (int mf = 0; mf < 4; ++mf) {
#pragma unroll
      for (int reg = 0; reg < 4; ++reg) {
        float best = acc[mf][0][reg] - cn[0];
        int   bc   = colLane;
#pragma unroll
        for (int nf = 1; nf < 4; ++nf) {
          float v = acc[mf][nf][reg] - cn[nf];
          int c2 = colLane + nf * 16;
          if (v > best || (v == best && c2 < bc)) { best = v; bc = c2; }
        }
#pragma unroll
        for (int m = 1; m < 16; m <<= 1) {
          float vo = __shfl_xor(best, m, 64);
          int   co = __shfl_xor(bc,   m, 64);
          if (vo > best || (vo == best && co < bc)) { best = vo; bc = co; }
        }
        if ((lane & 15) == 0) {
          int row = rowBase + wm * 64 + mf * 16 + ((lane >> 4) << 2) + reg;
          if (row < M) {
            pval[(size_t)row * nchunk + chunk] = best;
            pidx[(size_t)row * nchunk + chunk] = bc;
          }
        }
      }
    }
  } else {
    float bl[4];
#pragma unroll
    for (int nf = 0; nf < 4; ++nf) bl[nf] = cnb[colLane + nf * 16];
#pragma unroll
    for (int mf = 0; mf < 4; ++mf)
#pragma unroll
      for (int nf = 0; nf < 4; ++nf)
#pragma unroll
        for (int reg = 0; reg < 4; ++reg) {
          int row = rowBase + wm * 64 + mf * 16 + ((lane >> 4) << 2) + reg;
          if (row < M) {
            float v = acc[mf][nf][reg] + bl[nf];
            if (ACT) v = v > 0.f ? v : 0.01f * v;
            outb[(size_t)row * N + colLane + nf * 16] = rne_bf16(v);
          }
        }
  }
}

// -------------------------------------------------------------- small kernels

__global__ __launch_bounds__(256) void argmax_reduce(
    const float* __restrict__ pval, const int* __restrict__ pidx,
    int* __restrict__ idxOut, int nchunk)
{
  int row  = blockIdx.x * 4 + (threadIdx.x >> 6);
  int lane = threadIdx.x & 63;
  float v = pval[(size_t)row * nchunk + lane];
  int   c = pidx[(size_t)row * nchunk + lane];
#pragma unroll
  for (int m = 1; m < 64; m <<= 1) {
    float vo = __shfl_xor(v, m, 64);
    int   co = __shfl_xor(c, m, 64);
    if (vo > v || (vo == v && co < c)) { v = vo; c = co; }
  }
  if (lane == 0) idxOut[row] = c;
}

__global__ __launch_bounds__(256) void build_spk(
    const u16* __restrict__ xhi, const u16* __restrict__ xlo,
    const float* __restrict__ cent, const int* __restrict__ idx,
    u16* __restrict__ spk, int C)
{
  int row = blockIdx.x;
  const float* cr = cent + (size_t)idx[row] * C;
  size_t base = (size_t)row * C;
  for (int c = threadIdx.x; c < C; c += 256) {
    float v = b2f(xhi[base + c]) + b2f(xlo[base + c]) - cr[c];
    spk[base + c] = rne_bf16(v);
  }
}

__global__ __launch_bounds__(256) void transpose_out(
    const u16* __restrict__ spkdec, const float* __restrict__ cent,
    const int* __restrict__ idx, float* __restrict__ out, int C, int T)
{
  __shared__ float tile[64][65];
  int r0 = blockIdx.x * 64, c0 = blockIdx.y * 64;
#pragma unroll
  for (int i = 0; i < 16; ++i) {
    int id = threadIdx.x + i * 256;
    int lr = id >> 6, lc = id & 63;
    int row = r0 + lr;
    tile[lr][lc] = b2f(spkdec[(size_t)row * C + c0 + lc])
                 + cent[(size_t)idx[row] * C + c0 + lc];
  }
  __syncthreads();
#pragma unroll
  for (int i = 0; i < 16; ++i) {
    int id = threadIdx.x + i * 256;
    int lc = id >> 6, lr = id & 63;
    int row = r0 + lr;
    int b = row / T, t = row - b * T;
    out[((size_t)b * C + c0 + lc) * T + t] = tile[lr][lc];
  }
}

// --------------------------------------------------------------------- launch

extern "C" void kernel_launch(void* const* d_in, const int* in_sizes, int n_in,
                              void* d_out, int out_size, void* d_ws, size_t ws_size,
                              hipStream_t stream)
{
  const float* feature  = (const float*)d_in[0];
  const float* centroid = (const float*)d_in[1];
  const float* ew0 = (const float*)d_in[2];
  const float* eb0 = (const float*)d_in[3];
  const float* ew1 = (const float*)d_in[4];
  const float* eb1 = (const float*)d_in[5];
  const float* ew2 = (const float*)d_in[6];
  const float* eb2 = (const float*)d_in[7];
  const float* dw0 = (const float*)d_in[8];
  const float* db0 = (const float*)d_in[9];
  const float* dw1 = (const float*)d_in[10];
  const float* db1 = (const float*)d_in[11];
  const float* dw2 = (const float*)d_in[12];
  const float* db2 = (const float*)d_in[13];
  float* out = (float*)d_out;

  const int Bb = 16, C = 1024, T = 1500, M = Bb * T;    // M = 24000
  const int NBIN = 4096, HID = 512, EMB = 256;
  const int MB  = (M + 127) / 128;                      // 188
  const int MB2 = (M + 255) / 256;                      // 94

  char* ws = (char*)d_ws;
  size_t off = 0;
  auto alloc = [&](size_t bytes) -> char* {
    char* p = ws + off;
    off += (bytes + 255) & ~(size_t)255;
    return p;
  };
  u16*   c_hi  = (u16*)  alloc((size_t)NBIN * C * 2);
  u16*   c_lo  = (u16*)  alloc((size_t)NBIN * C * 2);
  float* cnorm = (float*)alloc((size_t)NBIN * 4);
  u16*   wb0   = (u16*)  alloc((size_t)HID * C   * 2);
  u16*   wb1   = (u16*)  alloc((size_t)HID * HID * 2);
  u16*   wb2   = (u16*)  alloc((size_t)EMB * HID * 2);
  u16*   wb3   = (u16*)  alloc((size_t)HID * EMB * 2);
  u16*   wb4   = (u16*)  alloc((size_t)HID * HID * 2);
  u16*   wb5   = (u16*)  alloc((size_t)C   * HID * 2);
  u16*   x_hi  = (u16*)  alloc((size_t)M * C * 2);
  u16*   x_lo  = (u16*)  alloc((size_t)M * C * 2);
  int*   idx   = (int*)  alloc((size_t)M * 4);
  char*  spkR  =         alloc((size_t)M * C * 2);
  u16*   spk   = (u16*)spkR;
  float* pval  = (float*)spkR;                          // overlay (pre-spk)
  int*   pidx  = (int*)(spkR + (size_t)M * 64 * 4);     // overlay (pre-spk)
  u16*   h1    = (u16*)  alloc((size_t)M * HID * 2);
  u16*   h2    = (u16*)  alloc((size_t)M * HID * 2);
  u16*   hz    = (u16*)  alloc((size_t)M * EMB * 2);

  conv_centroid<<<NBIN / 4, 256, 0, stream>>>(centroid, c_hi, c_lo, cnorm, C);
  conv_feature<<<dim3((T + 63) / 64, C / 64, Bb), 256, 0, stream>>>(feature, x_hi, x_lo, C, T);
  f2bf<<<(HID * C   + 255) / 256, 256, 0, stream>>>(ew0, wb0, HID * C);
  f2bf<<<(HID * HID + 255) / 256, 256, 0, stream>>>(ew1, wb1, HID * HID);
  f2bf<<<(EMB * HID + 255) / 256, 256, 0, stream>>>(ew2, wb2, EMB * HID);
  f2bf<<<(HID * EMB + 255) / 256, 256, 0, stream>>>(dw0, wb3, HID * EMB);
  f2bf<<<(HID * HID + 255) / 256, 256, 0, stream>>>(dw1, wb4, HID * HID);
  f2bf<<<(C   * HID + 255) / 256, 256, 0, stream>>>(dw2, wb5, C * HID);

  // score GEMM: 8-phase 256^2, segs hi.hi + lo.hi + hi.lo, fused partial argmax
  score256<1024, 3><<<dim3(NBIN / 256, MB2), 512, 0, stream>>>(
      x_hi, x_lo, x_hi, c_hi, c_hi, c_lo, cnorm, pval, pidx, M, NBIN);

  argmax_reduce<<<M / 4, 256, 0, stream>>>(pval, pidx, idx, NBIN / 64);
  build_spk<<<M, 256, 0, stream>>>(x_hi, x_lo, centroid, idx, spk, C);

  gemm_bt<1, false, true ><<<dim3(HID / 128, MB), 256, 0, stream>>>(
      spk, spk, spk, wb0, wb0, wb0, eb0, h1, nullptr, nullptr, M, HID, C);
  gemm_bt<1, false, true ><<<dim3(HID / 128, MB), 256, 0, stream>>>(
      h1, h1, h1, wb1, wb1, wb1, eb1, h2, nullptr, nullptr, M, HID, HID);
  gemm_bt<1, false, false><<<dim3(EMB / 128, MB), 256, 0, stream>>>(
      h2, h2, h2, wb2, wb2, wb2, eb2, hz, nullptr, nullptr, M, EMB, HID);
  gemm_bt<1, false, true ><<<dim3(HID / 128, MB), 256, 0, stream>>>(
      hz, hz, hz, wb3, wb3, wb3, db0, h1, nullptr, nullptr, M, HID, EMB);
  gemm_bt<1, false, true ><<<dim3(HID / 128, MB), 256, 0, stream>>>(
      h1, h1, h1, wb4, wb4, wb4, db1, h2, nullptr, nullptr, M, HID, HID);
  gemm_bt<1, false, false><<<dim3(C / 128, MB), 256, 0, stream>>>(
      h2, h2, h2, wb5, wb5, wb5, db2, spk, nullptr, nullptr, M, C, HID);

  transpose_out<<<dim3(M / 64, C / 64), 256, 0, stream>>>(spk, centroid, idx, out, C, T);
}

// Round 3
// 1015.588 us; speedup vs baseline: 1.1756x; 1.0696x over previous
//
#include <hip/hip_runtime.h>

// M02SameVQ: VQ nearest-centroid + residual MLP autoencoder, MI355X (gfx950).
//
// Round 3: score GEMM K-loop rebuilt as a faithful m201 8-phase template:
//   per phase: {ds_read quadrant subtile (12/4/8/0), stage ONE half-tile,
//               [lgkmcnt(8) if 12 reads], s_barrier, lgkmcnt(0)+sched_barrier(0),
//               setprio(1), 16 MFMA, setprio(0), s_barrier}
//   quadrant order (0,0)->(0,1)->(1,1)->(1,0) chains operand reuse;
//   stage stream: ph1 A0(t+1) ph2 A1(t+1) ph3 B0(t+2) ph4 B1(t+2)
//                 ph5 A0(t+2) ph6 A1(t+2) ph7 B0(t+3) ph8 B1(t+3)
//   vmcnt(4) at ph4/ph8 only (ledger-verified: each buffer's 4 halves land
//   before its compute block; re-stage only after that buffer's reads drain,
//   barrier-ordered cross-wave).
// MLP GEMMs keep the 128^2 m97 structure.

typedef unsigned short u16;
typedef unsigned int   u32;
typedef __bf16 bf16x8 __attribute__((ext_vector_type(8)));
typedef float  f32x4  __attribute__((ext_vector_type(4)));

#define AS1 __attribute__((address_space(1)))
#define AS3 __attribute__((address_space(3)))

__device__ __forceinline__ u16 rne_bf16(float f) {
  u32 u = __float_as_uint(f);
  u = (u + 0x7FFFu + ((u >> 16) & 1u)) >> 16;
  return (u16)u;
}
__device__ __forceinline__ float b2f(u16 h) {
  return __uint_as_float(((u32)h) << 16);
}

// ---------------------------------------------------------------- conversions

__global__ __launch_bounds__(256) void conv_centroid(
    const float* __restrict__ cent, u16* __restrict__ chi, u16* __restrict__ clo,
    float* __restrict__ cnorm, int K)
{
  int row  = blockIdx.x * 4 + (threadIdx.x >> 6);
  int lane = threadIdx.x & 63;
  const float* cr = cent + (size_t)row * K;
  float s = 0.f;
  for (int j = 0; j < K; j += 64) {
    int k = j + lane;
    float f = cr[k];
    s += f * f;
    u32 u = __float_as_uint(f);
    u32 hi = (u + 0x7FFFu + ((u >> 16) & 1u)) >> 16;
    float fhi = __uint_as_float(hi << 16);
    chi[(size_t)row * K + k] = (u16)hi;
    clo[(size_t)row * K + k] = rne_bf16(f - fhi);
  }
#pragma unroll
  for (int m = 1; m < 64; m <<= 1) s += __shfl_xor(s, m, 64);
  if (lane == 0) cnorm[row] = s;
}

__global__ __launch_bounds__(256) void conv_feature(
    const float* __restrict__ feat, u16* __restrict__ xhi, u16* __restrict__ xlo,
    int C, int T)
{
  __shared__ float tile[64][65];
  int bb = blockIdx.z, c0 = blockIdx.y * 64, t0 = blockIdx.x * 64;
  const float* fb = feat + (size_t)bb * C * T;
#pragma unroll
  for (int i = 0; i < 16; ++i) {
    int id = threadIdx.x + i * 256;
    int lc = id >> 6, lt = id & 63;
    int t = t0 + lt;
    tile[lc][lt] = (t < T) ? fb[(size_t)(c0 + lc) * T + t] : 0.f;
  }
  __syncthreads();
#pragma unroll
  for (int i = 0; i < 16; ++i) {
    int id = threadIdx.x + i * 256;
    int lt = id >> 6, lc = id & 63;
    int t = t0 + lt;
    if (t < T) {
      size_t row = (size_t)bb * T + t;
      float f = tile[lc][lt];
      u32 u = __float_as_uint(f);
      u32 hi = (u + 0x7FFFu + ((u >> 16) & 1u)) >> 16;
      float fhi = __uint_as_float(hi << 16);
      xhi[row * C + c0 + lc] = (u16)hi;
      xlo[row * C + c0 + lc] = rne_bf16(f - fhi);
    }
  }
}

__global__ __launch_bounds__(256) void f2bf(
    const float* __restrict__ s, u16* __restrict__ d, int n)
{
  int i = blockIdx.x * 256 + threadIdx.x;
  if (i < n) d[i] = rne_bf16(s[i]);
}

// ----------------------------------------------------- 256^2 8-phase score GEMM

template<int KK, int NSEG>
__global__ __launch_bounds__(512, 2) void score256(
    const u16* __restrict__ A0, const u16* __restrict__ A1, const u16* __restrict__ A2,
    const u16* __restrict__ B0s, const u16* __restrict__ B1s, const u16* __restrict__ B2s,
    const float* __restrict__ cnb, float* __restrict__ pval, int* __restrict__ pidx,
    int M, int N)
{
  constexpr int NKTPS = KK / 64;
  constexpr int NKT   = NSEG * NKTPS;
  static_assert(NKT % 2 == 0, "even tile count");

  __shared__ f32x4 smem4[8192];             // 128 KiB
  char* smem = (char*)smem4;
  // layout: A buf0 [0,32K) | A buf1 [32K,64K) | B buf0 [64K,96K) | B buf1 [96K,128K)

  const int lane = threadIdx.x & 63;
  const int wid  = threadIdx.x >> 6;        // 0..7
  const int wr   = wid >> 2;                // 0..1 (M)
  const int wc   = wid & 3;                 // 0..3 (N)

  const int rowBase = blockIdx.y * 256;
  const int colBase = blockIdx.x * 256;

  const int kswz  = ((lane & 7) ^ (lane >> 3)) << 4;  // pre-swizzled source k
  const int kbase = (lane >> 4) << 4;                 // frag k-byte 0/16/32/48

  const f32x4 zero4 = {0.f, 0.f, 0.f, 0.f};
  f32x4 acc[8][4];
#pragma unroll
  for (int i = 0; i < 8; ++i)
#pragma unroll
    for (int j = 0; j < 4; ++j) acc[i][j] = zero4;

  bf16x8 aR[4][2];      // single set, reloaded per a-quadrant
  bf16x8 bR[2][2][2];   // [qn][nf][kh], both qn sets live (b0 spans ph1..ph4)

  // ---- staging: half h (0/1) of tile t into buffer b. 2 loads/wave.
  auto stageA = [&](int b, int h, int t) {
    int tc  = t < NKT ? t : NKT - 1;
    int seg = tc / NKTPS;
    int k0  = (tc - seg * NKTPS) << 6;
    const u16* S = (seg == 0 ? A0 : (seg == 1 ? A1 : A2));
    char* dst = smem + b * 32768 + h * 16384 + wid * 1024;
#pragma unroll
    for (int j = 0; j < 2; ++j) {
      int r  = h * 128 + j * 64 + wid * 8 + (lane >> 3);
      int gr = rowBase + r; gr = gr < M ? gr : M - 1;
      const char* ga = (const char*)S + ((size_t)gr * KK + k0) * 2 + kswz;
      __builtin_amdgcn_global_load_lds((const AS1 void*)ga,
                                       (AS3 void*)(dst + j * 8192), 16, 0, 0);
    }
  };
  auto stageB = [&](int b, int h, int t) {
    int tc  = t < NKT ? t : NKT - 1;
    int seg = tc / NKTPS;
    int k0  = (tc - seg * NKTPS) << 6;
    const u16* S = (seg == 0 ? B0s : (seg == 1 ? B1s : B2s));
    char* dst = smem + 65536 + b * 32768 + h * 16384 + wid * 1024;
#pragma unroll
    for (int j = 0; j < 2; ++j) {
      int r  = h * 128 + j * 64 + wid * 8 + (lane >> 3);
      int gr = colBase + r;                 // N multiple of 128
      const char* ga = (const char*)S + ((size_t)gr * KK + k0) * 2 + kswz;
      __builtin_amdgcn_global_load_lds((const AS1 void*)ga,
                                       (AS3 void*)(dst + j * 8192), 16, 0, 0);
    }
  };

#define LDA_Q(b, qm) do { \
  _Pragma("unroll") for (int mf = 0; mf < 4; ++mf) { \
    int row = wr * 128 + (qm) * 64 + mf * 16 + (lane & 15); \
    const char* p = smem + (b) * 32768 + row * 128; \
    int sw = (row & 7) << 4; \
    aR[mf][0] = *(const bf16x8*)(p + (kbase ^ sw)); \
    aR[mf][1] = *(const bf16x8*)(p + ((kbase + 64) ^ sw)); \
  } } while (0)

#define LDB_Q(b, qn) do { \
  _Pragma("unroll") for (int nf = 0; nf < 2; ++nf) { \
    int row = wc * 64 + (qn) * 32 + nf * 16 + (lane & 15); \
    const char* p = smem + 65536 + (b) * 32768 + row * 128; \
    int sw = (row & 7) << 4; \
    bR[qn][nf][0] = *(const bf16x8*)(p + (kbase ^ sw)); \
    bR[qn][nf][1] = *(const bf16x8*)(p + ((kbase + 64) ^ sw)); \
  } } while (0)

#define MMQ(qm, qn) do { \
  _Pragma("unroll") for (int mf = 0; mf < 4; ++mf) \
  _Pragma("unroll") for (int nf = 0; nf < 2; ++nf) { \
    acc[(qm)*4+mf][(qn)*2+nf] = __builtin_amdgcn_mfma_f32_16x16x32_bf16( \
        aR[mf][0], bR[qn][nf][0], acc[(qm)*4+mf][(qn)*2+nf], 0, 0, 0); \
    acc[(qm)*4+mf][(qn)*2+nf] = __builtin_amdgcn_mfma_f32_16x16x32_bf16( \
        aR[mf][1], bR[qn][nf][1], acc[(qm)*4+mf][(qn)*2+nf], 0, 0, 0); \
  } } while (0)

#define BAR()     __builtin_amdgcn_s_barrier()
#define PRIO1()   __builtin_amdgcn_s_setprio(1)
#define PRIO0()   __builtin_amdgcn_s_setprio(0)
#define VMCNT4()  asm volatile("s_waitcnt vmcnt(4)" ::: "memory")
#define LGKM8()   asm volatile("s_waitcnt lgkmcnt(8)" ::: "memory")
#define LGKM0_SB() do { asm volatile("s_waitcnt lgkmcnt(0)" ::: "memory"); \
                        __builtin_amdgcn_sched_barrier(0); } while (0)

  // ---- prologue: tile0 (buf0) all 4 halves + tile1 (buf1) B halves.
  stageA(0, 0, 0); stageA(0, 1, 0); stageB(0, 0, 0); stageB(0, 1, 0);
  stageB(1, 0, 1); stageB(1, 1, 1);
  VMCNT4();                                 // tile0 landed; tile1-B in flight
  BAR();

  // ---- main loop: 2 K-tiles (8 phases) per iteration.
  for (int i = 0; i < NKT / 2; ++i) {
    const int t = 2 * i;
    // ph1: buf0 quad(0,0) — 12 reads
    LDA_Q(0, 0); LDB_Q(0, 0);
    stageA(1, 0, t + 1);
    LGKM8();
    BAR(); LGKM0_SB(); PRIO1(); MMQ(0, 0); PRIO0(); BAR();
    // ph2: quad(0,1) — 4 reads
    LDB_Q(0, 1);
    stageA(1, 1, t + 1);
    BAR(); LGKM0_SB(); PRIO1(); MMQ(0, 1); PRIO0(); BAR();
    // ph3: quad(1,1) — 8 reads
    LDA_Q(0, 1);
    stageB(0, 0, t + 2);
    BAR(); LGKM0_SB(); PRIO1(); MMQ(1, 1); PRIO0(); BAR();
    // ph4: quad(1,0) — 0 reads; gate tile t+1
    stageB(0, 1, t + 2);
    VMCNT4();
    BAR(); PRIO1(); MMQ(1, 0); PRIO0(); BAR();
    // ph5: buf1 quad(0,0) — 12 reads
    LDA_Q(1, 0); LDB_Q(1, 0);
    stageA(0, 0, t + 2);
    LGKM8();
    BAR(); LGKM0_SB(); PRIO1(); MMQ(0, 0); PRIO0(); BAR();
    // ph6: quad(0,1) — 4 reads
    LDB_Q(1, 1);
    stageA(0, 1, t + 2);
    BAR(); LGKM0_SB(); PRIO1(); MMQ(0, 1); PRIO0(); BAR();
    // ph7: quad(1,1) — 8 reads
    LDA_Q(1, 1);
    stageB(1, 0, t + 3);
    BAR(); LGKM0_SB(); PRIO1(); MMQ(1, 1); PRIO0(); BAR();
    // ph8: quad(1,0) — 0 reads; gate tile t+2
    stageB(1, 1, t + 3);
    VMCNT4();
    BAR(); PRIO1(); MMQ(1, 0); PRIO0(); BAR();
  }

  // ---- epilogue: fused partial argmax of (acc - 0.5*c_norm) per 64-col chunk.
  const int colL = colBase + wc * 64 + (lane & 15);
  float cn[4];
#pragma unroll
  for (int ni = 0; ni < 4; ++ni) cn[ni] = 0.5f * cnb[colL + ni * 16];
  const int nchunk = N >> 6;
  const int chunk  = (colBase >> 6) + wc;
#pragma unroll
  for (int mi = 0; mi < 8; ++mi) {
#pragma unroll
    for (int reg = 0; reg < 4; ++reg) {
      float best = acc[mi][0][reg] - cn[0];
      int   bc   = colL;
#pragma unroll
      for (int ni = 1; ni < 4; ++ni) {
        float v  = acc[mi][ni][reg] - cn[ni];
        int   c2 = colL + ni * 16;
        if (v > best || (v == best && c2 < bc)) { best = v; bc = c2; }
      }
#pragma unroll
      for (int m = 1; m < 16; m <<= 1) {
        float vo = __shfl_xor(best, m, 64);
        int   co = __shfl_xor(bc,   m, 64);
        if (vo > best || (vo == best && co < bc)) { best = vo; bc = co; }
      }
      if ((lane & 15) == 0) {
        int row = rowBase + wr * 128 + (mi >> 2) * 64 + (mi & 3) * 16
                + ((lane >> 4) << 2) + reg;
        if (row < M) {
          pval[(size_t)row * nchunk + chunk] = best;
          pidx[(size_t)row * nchunk + chunk] = bc;
        }
      }
    }
  }
#undef LDA_Q
#undef LDB_Q
#undef MMQ
#undef BAR
#undef PRIO1
#undef PRIO0
#undef VMCNT4
#undef LGKM8
#undef LGKM0_SB
}

// ------------------------------------------------- 128^2 GEMM (MLP layers)

template<int NSEG, bool SCORE, bool ACT>
__global__ __launch_bounds__(256) void gemm_bt(
    const u16* __restrict__ A0, const u16* __restrict__ A1, const u16* __restrict__ A2,
    const u16* __restrict__ B0, const u16* __restrict__ B1, const u16* __restrict__ B2,
    const float* __restrict__ cnb, u16* __restrict__ outb,
    float* __restrict__ pval, int* __restrict__ pidx,
    int M, int N, int K)
{
  __shared__ bf16x8 smem8[2048];            // 32 KiB: A [0,16K), B [16K,32K)
  char* smem = (char*)smem8;

  const int lane = threadIdx.x & 63;
  const int wid  = threadIdx.x >> 6;
  const int wm   = wid >> 1, wn = wid & 1;

  const int rowBase = blockIdx.y * 128;
  const int colBase = blockIdx.x * 128;

  const f32x4 zero4 = {0.f, 0.f, 0.f, 0.f};
  f32x4 acc[4][4];
#pragma unroll
  for (int i = 0; i < 4; ++i)
#pragma unroll
    for (int j = 0; j < 4; ++j) acc[i][j] = zero4;

  const int l8   = lane >> 3;
  const int kbsw = ((lane & 7) ^ l8) << 4;
  const int kseg = K >> 6;
  const int nkt  = NSEG * kseg;

  for (int kt = 0; kt < nkt; ++kt) {
    int seg, k0;
    if (NSEG == 1) { seg = 0; k0 = kt << 6; }
    else           { seg = kt / kseg; k0 = (kt - seg * kseg) << 6; }
    const u16* Aseg = (seg == 0) ? A0 : (seg == 1 ? A1 : A2);
    const u16* Bseg = (seg == 0) ? B0 : (seg == 1 ? B1 : B2);

#pragma unroll
    for (int i = 0; i < 4; ++i) {
      int c = wid * 4 + i;
      int r = c * 8 + l8;
      int gra = rowBase + r; gra = gra < M ? gra : (M - 1);
      const char* ga = (const char*)Aseg + ((size_t)gra * K + k0) * 2 + kbsw;
      __builtin_amdgcn_global_load_lds((const AS1 void*)ga,
                                       (AS3 void*)(smem + c * 1024), 16, 0, 0);
      int grb = colBase + r;
      const char* gb = (const char*)Bseg + ((size_t)grb * K + k0) * 2 + kbsw;
      __builtin_amdgcn_global_load_lds((const AS1 void*)gb,
                                       (AS3 void*)(smem + 16384 + c * 1024), 16, 0, 0);
    }
    __syncthreads();

#pragma unroll
    for (int kk = 0; kk < 64; kk += 32) {
      bf16x8 a[4], b[4];
      const int kb = (kk + ((lane >> 4) << 3)) << 1;
#pragma unroll
      for (int mf = 0; mf < 4; ++mf) {
        int row = wm * 64 + mf * 16 + (lane & 15);
        a[mf] = *(const bf16x8*)(smem + row * 128 + (kb ^ ((row & 7) << 4)));
      }
#pragma unroll
      for (int nf = 0; nf < 4; ++nf) {
        int row = wn * 64 + nf * 16 + (lane & 15);
        b[nf] = *(const bf16x8*)(smem + 16384 + row * 128 + (kb ^ ((row & 7) << 4)));
      }
#pragma unroll
      for (int mf = 0; mf < 4; ++mf)
#pragma unroll
        for (int nf = 0; nf < 4; ++nf)
          acc[mf][nf] = __builtin_amdgcn_mfma_f32_16x16x32_bf16(
              a[mf], b[nf], acc[mf][nf], 0, 0, 0);
    }
    __syncthreads();
  }

  const int colLane = colBase + wn * 64 + (lane & 15);

  if (SCORE) {
    float cn[4];
#pragma unroll
    for (int nf = 0; nf < 4; ++nf) cn[nf] = 0.5f * cnb[colLane + nf * 16];
    const int nchunk = N >> 6;
    const int chunk  = (colBase >> 6) + wn;
#pragma unroll
    for (int mf = 0; mf < 4; ++mf) {
#pragma unroll
      for (int reg = 0; reg < 4; ++reg) {
        float best = acc[mf][0][reg] - cn[0];
        int   bc   = colLane;
#pragma unroll
        for (int nf = 1; nf < 4; ++nf) {
          float v = acc[mf][nf][reg] - cn[nf];
          int c2 = colLane + nf * 16;
          if (v > best || (v == best && c2 < bc)) { best = v; bc = c2; }
        }
#pragma unroll
        for (int m = 1; m < 16; m <<= 1) {
          float vo = __shfl_xor(best, m, 64);
          int   co = __shfl_xor(bc,   m, 64);
          if (vo > best || (vo == best && co < bc)) { best = vo; bc = co; }
        }
        if ((lane & 15) == 0) {
          int row = rowBase + wm * 64 + mf * 16 + ((lane >> 4) << 2) + reg;
          if (row < M) {
            pval[(size_t)row * nchunk + chunk] = best;
            pidx[(size_t)row * nchunk + chunk] = bc;
          }
        }
      }
    }
  } else {
    float bl[4];
#pragma unroll
    for (int nf = 0; nf < 4; ++nf) bl[nf] = cnb[colLane + nf * 16];
#pragma unroll
    for (int mf = 0; mf < 4; ++mf)
#pragma unroll
      for (int nf = 0; nf < 4; ++nf)
#pragma unroll
        for (int reg = 0; reg < 4; ++reg) {
          int row = rowBase + wm * 64 + mf * 16 + ((lane >> 4) << 2) + reg;
          if (row < M) {
            float v = acc[mf][nf][reg] + bl[nf];
            if (ACT) v = v > 0.f ? v : 0.01f * v;
            outb[(size_t)row * N + colLane + nf * 16] = rne_bf16(v);
          }
        }
  }
}

// -------------------------------------------------------------- small kernels

__global__ __launch_bounds__(256) void argmax_reduce(
    const float* __restrict__ pval, const int* __restrict__ pidx,
    int* __restrict__ idxOut, int nchunk)
{
  int row  = blockIdx.x * 4 + (threadIdx.x >> 6);
  int lane = threadIdx.x & 63;
  float v = pval[(size_t)row * nchunk + lane];
  int   c = pidx[(size_t)row * nchunk + lane];
#pragma unroll
  for (int m = 1; m < 64; m <<= 1) {
    float vo = __shfl_xor(v, m, 64);
    int   co = __shfl_xor(c, m, 64);
    if (vo > v || (vo == v && co < c)) { v = vo; c = co; }
  }
  if (lane == 0) idxOut[row] = c;
}

__global__ __launch_bounds__(256) void build_spk(
    const u16* __restrict__ xhi, const u16* __restrict__ xlo,
    const float* __restrict__ cent, const int* __restrict__ idx,
    u16* __restrict__ spk, int C)
{
  int row = blockIdx.x;
  const float* cr = cent + (size_t)idx[row] * C;
  size_t base = (size_t)row * C;
  for (int c = threadIdx.x; c < C; c += 256) {
    float v = b2f(xhi[base + c]) + b2f(xlo[base + c]) - cr[c];
    spk[base + c] = rne_bf16(v);
  }
}

__global__ __launch_bounds__(256) void transpose_out(
    const u16* __restrict__ spkdec, const float* __restrict__ cent,
    const int* __restrict__ idx, float* __restrict__ out, int C, int T)
{
  __shared__ float tile[64][65];
  int r0 = blockIdx.x * 64, c0 = blockIdx.y * 64;
#pragma unroll
  for (int i = 0; i < 16; ++i) {
    int id = threadIdx.x + i * 256;
    int lr = id >> 6, lc = id & 63;
    int row = r0 + lr;
    tile[lr][lc] = b2f(spkdec[(size_t)row * C + c0 + lc])
                 + cent[(size_t)idx[row] * C + c0 + lc];
  }
  __syncthreads();
#pragma unroll
  for (int i = 0; i < 16; ++i) {
    int id = threadIdx.x + i * 256;
    int lc = id >> 6, lr = id & 63;
    int row = r0 + lr;
    int b = row / T, t = row - b * T;
    out[((size_t)b * C + c0 + lc) * T + t] = tile[lr][lc];
  }
}

// --------------------------------------------------------------------- launch

extern "C" void kernel_launch(void* const* d_in, const int* in_sizes, int n_in,
                              void* d_out, int out_size, void* d_ws, size_t ws_size,
                              hipStream_t stream)
{
  const float* feature  = (const float*)d_in[0];
  const float* centroid = (const float*)d_in[1];
  const float* ew0 = (const float*)d_in[2];
  const float* eb0 = (const float*)d_in[3];
  const float* ew1 = (const float*)d_in[4];
  const float* eb1 = (const float*)d_in[5];
  const float* ew2 = (const float*)d_in[6];
  const float* eb2 = (const float*)d_in[7];
  const float* dw0 = (const float*)d_in[8];
  const float* db0 = (const float*)d_in[9];
  const float* dw1 = (const float*)d_in[10];
  const float* db1 = (const float*)d_in[11];
  const float* dw2 = (const float*)d_in[12];
  const float* db2 = (const float*)d_in[13];
  float* out = (float*)d_out;

  const int Bb = 16, C = 1024, T = 1500, M = Bb * T;    // M = 24000
  const int NBIN = 4096, HID = 512, EMB = 256;
  const int MB  = (M + 127) / 128;                      // 188
  const int MB2 = (M + 255) / 256;                      // 94

  char* ws = (char*)d_ws;
  size_t off = 0;
  auto alloc = [&](size_t bytes) -> char* {
    char* p = ws + off;
    off += (bytes + 255) & ~(size_t)255;
    return p;
  };
  u16*   c_hi  = (u16*)  alloc((size_t)NBIN * C * 2);
  u16*   c_lo  = (u16*)  alloc((size_t)NBIN * C * 2);
  float* cnorm = (float*)alloc((size_t)NBIN * 4);
  u16*   wb0   = (u16*)  alloc((size_t)HID * C   * 2);
  u16*   wb1   = (u16*)  alloc((size_t)HID * HID * 2);
  u16*   wb2   = (u16*)  alloc((size_t)EMB * HID * 2);
  u16*   wb3   = (u16*)  alloc((size_t)HID * EMB * 2);
  u16*   wb4   = (u16*)  alloc((size_t)HID * HID * 2);
  u16*   wb5   = (u16*)  alloc((size_t)C   * HID * 2);
  u16*   x_hi  = (u16*)  alloc((size_t)M * C * 2);
  u16*   x_lo  = (u16*)  alloc((size_t)M * C * 2);
  int*   idx   = (int*)  alloc((size_t)M * 4);
  char*  spkR  =         alloc((size_t)M * C * 2);
  u16*   spk   = (u16*)spkR;
  float* pval  = (float*)spkR;                          // overlay (pre-spk)
  int*   pidx  = (int*)(spkR + (size_t)M * 64 * 4);     // overlay (pre-spk)
  u16*   h1    = (u16*)  alloc((size_t)M * HID * 2);
  u16*   h2    = (u16*)  alloc((size_t)M * HID * 2);
  u16*   hz    = (u16*)  alloc((size_t)M * EMB * 2);

  conv_centroid<<<NBIN / 4, 256, 0, stream>>>(centroid, c_hi, c_lo, cnorm, C);
  conv_feature<<<dim3((T + 63) / 64, C / 64, Bb), 256, 0, stream>>>(feature, x_hi, x_lo, C, T);
  f2bf<<<(HID * C   + 255) / 256, 256, 0, stream>>>(ew0, wb0, HID * C);
  f2bf<<<(HID * HID + 255) / 256, 256, 0, stream>>>(ew1, wb1, HID * HID);
  f2bf<<<(EMB * HID + 255) / 256, 256, 0, stream>>>(ew2, wb2, EMB * HID);
  f2bf<<<(HID * EMB + 255) / 256, 256, 0, stream>>>(dw0, wb3, HID * EMB);
  f2bf<<<(HID * HID + 255) / 256, 256, 0, stream>>>(dw1, wb4, HID * HID);
  f2bf<<<(C   * HID + 255) / 256, 256, 0, stream>>>(dw2, wb5, C * HID);

  // score GEMM: 8-phase 256^2, segs hi.hi + lo.hi + hi.lo, fused partial argmax
  score256<1024, 3><<<dim3(NBIN / 256, MB2), 512, 0, stream>>>(
      x_hi, x_lo, x_hi, c_hi, c_hi, c_lo, cnorm, pval, pidx, M, NBIN);

  argmax_reduce<<<M / 4, 256, 0, stream>>>(pval, pidx, idx, NBIN / 64);
  build_spk<<<M, 256, 0, stream>>>(x_hi, x_lo, centroid, idx, spk, C);

  gemm_bt<1, false, true ><<<dim3(HID / 128, MB), 256, 0, stream>>>(
      spk, spk, spk, wb0, wb0, wb0, eb0, h1, nullptr, nullptr, M, HID, C);
  gemm_bt<1, false, true ><<<dim3(HID / 128, MB), 256, 0, stream>>>(
      h1, h1, h1, wb1, wb1, wb1, eb1, h2, nullptr, nullptr, M, HID, HID);
  gemm_bt<1, false, false><<<dim3(EMB / 128, MB), 256, 0, stream>>>(
      h2, h2, h2, wb2, wb2, wb2, eb2, hz, nullptr, nullptr, M, EMB, HID);
  gemm_bt<1, false, true ><<<dim3(HID / 128, MB), 256, 0, stream>>>(
      hz, hz, hz, wb3, wb3, wb3, db0, h1, nullptr, nullptr, M, HID, EMB);
  gemm_bt<1, false, true ><<<dim3(HID / 128, MB), 256, 0, stream>>>(
      h1, h1, h1, wb4, wb4, wb4, db1, h2, nullptr, nullptr, M, HID, HID);
  gemm_bt<1, false, false><<<dim3(C / 128, MB), 256, 0, stream>>>(
      h2, h2, h2, wb5, wb5, wb5, db2, spk, nullptr, nullptr, M, C, HID);

  transpose_out<<<dim3(M / 64, C / 64), 256, 0, stream>>>(spk, centroid, idx, out, C, T);
}

// Round 4
// 943.902 us; speedup vs baseline: 1.2649x; 1.0759x over previous
//
#include <hip/hip_runtime.h>

// M02SameVQ: VQ nearest-centroid + residual MLP autoencoder, MI355X (gfx950).
//
// Round 4: two-pass argmin.
//   Pass 1: score256<K,1> computes 1-term approx scores s1 = x_hi.c_hi - 0.5|c|^2
//           with fused per-64-col-chunk argmax (as before). 1/3 the MFMA work.
//   cand_select: per row, chunks with chunkmax >= rowmax - 1.0 (= 2B, B=0.5,
//           ~12 sigma over the 1-term error) -> per-chunk row lists (atomics).
//   rescan: for each (row, candidate chunk), EXACT 3-term scores
//           (hi.hi + lo.hi + hi.lo, same segment order / same MFMA as the
//           round-3 kernel => bit-identical scores) over the whole 64-centroid
//           chunk; per-row chunk best -> pval2/pidx2 ( -inf-init via 0xFE ).
//   argmax_reduce on pval2/pidx2 -> idx (bit-identical to round 3's idx).
// MLP GEMMs keep the 128^2 m97 structure; score256 keeps the 8-phase schedule.

typedef unsigned short u16;
typedef unsigned int   u32;
typedef __bf16 bf16x8 __attribute__((ext_vector_type(8)));
typedef float  f32x4  __attribute__((ext_vector_type(4)));

#define AS1 __attribute__((address_space(1)))
#define AS3 __attribute__((address_space(3)))

#define LIST_CAP 2048

__device__ __forceinline__ u16 rne_bf16(float f) {
  u32 u = __float_as_uint(f);
  u = (u + 0x7FFFu + ((u >> 16) & 1u)) >> 16;
  return (u16)u;
}
__device__ __forceinline__ float b2f(u16 h) {
  return __uint_as_float(((u32)h) << 16);
}

// ---------------------------------------------------------------- conversions

__global__ __launch_bounds__(256) void conv_centroid(
    const float* __restrict__ cent, u16* __restrict__ chi, u16* __restrict__ clo,
    float* __restrict__ cnorm, int K)
{
  int row  = blockIdx.x * 4 + (threadIdx.x >> 6);
  int lane = threadIdx.x & 63;
  const float* cr = cent + (size_t)row * K;
  float s = 0.f;
  for (int j = 0; j < K; j += 64) {
    int k = j + lane;
    float f = cr[k];
    s += f * f;
    u32 u = __float_as_uint(f);
    u32 hi = (u + 0x7FFFu + ((u >> 16) & 1u)) >> 16;
    float fhi = __uint_as_float(hi << 16);
    chi[(size_t)row * K + k] = (u16)hi;
    clo[(size_t)row * K + k] = rne_bf16(f - fhi);
  }
#pragma unroll
  for (int m = 1; m < 64; m <<= 1) s += __shfl_xor(s, m, 64);
  if (lane == 0) cnorm[row] = s;
}

__global__ __launch_bounds__(256) void conv_feature(
    const float* __restrict__ feat, u16* __restrict__ xhi, u16* __restrict__ xlo,
    int C, int T)
{
  __shared__ float tile[64][65];
  int bb = blockIdx.z, c0 = blockIdx.y * 64, t0 = blockIdx.x * 64;
  const float* fb = feat + (size_t)bb * C * T;
#pragma unroll
  for (int i = 0; i < 16; ++i) {
    int id = threadIdx.x + i * 256;
    int lc = id >> 6, lt = id & 63;
    int t = t0 + lt;
    tile[lc][lt] = (t < T) ? fb[(size_t)(c0 + lc) * T + t] : 0.f;
  }
  __syncthreads();
#pragma unroll
  for (int i = 0; i < 16; ++i) {
    int id = threadIdx.x + i * 256;
    int lt = id >> 6, lc = id & 63;
    int t = t0 + lt;
    if (t < T) {
      size_t row = (size_t)bb * T + t;
      float f = tile[lc][lt];
      u32 u = __float_as_uint(f);
      u32 hi = (u + 0x7FFFu + ((u >> 16) & 1u)) >> 16;
      float fhi = __uint_as_float(hi << 16);
      xhi[row * C + c0 + lc] = (u16)hi;
      xlo[row * C + c0 + lc] = rne_bf16(f - fhi);
    }
  }
}

__global__ __launch_bounds__(256) void f2bf(
    const float* __restrict__ s, u16* __restrict__ d, int n)
{
  int i = blockIdx.x * 256 + threadIdx.x;
  if (i < n) d[i] = rne_bf16(s[i]);
}

// ----------------------------------------------------- 256^2 8-phase score GEMM

template<int KK, int NSEG>
__global__ __launch_bounds__(512, 2) void score256(
    const u16* __restrict__ A0, const u16* __restrict__ A1, const u16* __restrict__ A2,
    const u16* __restrict__ B0s, const u16* __restrict__ B1s, const u16* __restrict__ B2s,
    const float* __restrict__ cnb, float* __restrict__ pval, int* __restrict__ pidx,
    int M, int N)
{
  constexpr int NKTPS = KK / 64;
  constexpr int NKT   = NSEG * NKTPS;
  static_assert(NKT % 2 == 0, "even tile count");

  __shared__ f32x4 smem4[8192];             // 128 KiB
  char* smem = (char*)smem4;
  // layout: A buf0 [0,32K) | A buf1 [32K,64K) | B buf0 [64K,96K) | B buf1 [96K,128K)

  const int lane = threadIdx.x & 63;
  const int wid  = threadIdx.x >> 6;        // 0..7
  const int wr   = wid >> 2;                // 0..1 (M)
  const int wc   = wid & 3;                 // 0..3 (N)

  const int rowBase = blockIdx.y * 256;
  const int colBase = blockIdx.x * 256;

  const int kswz  = ((lane & 7) ^ (lane >> 3)) << 4;  // pre-swizzled source k
  const int kbase = (lane >> 4) << 4;                 // frag k-byte 0/16/32/48

  const f32x4 zero4 = {0.f, 0.f, 0.f, 0.f};
  f32x4 acc[8][4];
#pragma unroll
  for (int i = 0; i < 8; ++i)
#pragma unroll
    for (int j = 0; j < 4; ++j) acc[i][j] = zero4;

  bf16x8 aR[4][2];      // single set, reloaded per a-quadrant
  bf16x8 bR[2][2][2];   // [qn][nf][kh]

  auto stageA = [&](int b, int h, int t) {
    int tc  = t < NKT ? t : NKT - 1;
    int seg = tc / NKTPS;
    int k0  = (tc - seg * NKTPS) << 6;
    const u16* S = (seg == 0 ? A0 : (seg == 1 ? A1 : A2));
    char* dst = smem + b * 32768 + h * 16384 + wid * 1024;
#pragma unroll
    for (int j = 0; j < 2; ++j) {
      int r  = h * 128 + j * 64 + wid * 8 + (lane >> 3);
      int gr = rowBase + r; gr = gr < M ? gr : M - 1;
      const char* ga = (const char*)S + ((size_t)gr * KK + k0) * 2 + kswz;
      __builtin_amdgcn_global_load_lds((const AS1 void*)ga,
                                       (AS3 void*)(dst + j * 8192), 16, 0, 0);
    }
  };
  auto stageB = [&](int b, int h, int t) {
    int tc  = t < NKT ? t : NKT - 1;
    int seg = tc / NKTPS;
    int k0  = (tc - seg * NKTPS) << 6;
    const u16* S = (seg == 0 ? B0s : (seg == 1 ? B1s : B2s));
    char* dst = smem + 65536 + b * 32768 + h * 16384 + wid * 1024;
#pragma unroll
    for (int j = 0; j < 2; ++j) {
      int r  = h * 128 + j * 64 + wid * 8 + (lane >> 3);
      int gr = colBase + r;
      const char* ga = (const char*)S + ((size_t)gr * KK + k0) * 2 + kswz;
      __builtin_amdgcn_global_load_lds((const AS1 void*)ga,
                                       (AS3 void*)(dst + j * 8192), 16, 0, 0);
    }
  };

#define LDA_Q(b, qm) do { \
  _Pragma("unroll") for (int mf = 0; mf < 4; ++mf) { \
    int row = wr * 128 + (qm) * 64 + mf * 16 + (lane & 15); \
    const char* p = smem + (b) * 32768 + row * 128; \
    int sw = (row & 7) << 4; \
    aR[mf][0] = *(const bf16x8*)(p + (kbase ^ sw)); \
    aR[mf][1] = *(const bf16x8*)(p + ((kbase + 64) ^ sw)); \
  } } while (0)

#define LDB_Q(b, qn) do { \
  _Pragma("unroll") for (int nf = 0; nf < 2; ++nf) { \
    int row = wc * 64 + (qn) * 32 + nf * 16 + (lane & 15); \
    const char* p = smem + 65536 + (b) * 32768 + row * 128; \
    int sw = (row & 7) << 4; \
    bR[qn][nf][0] = *(const bf16x8*)(p + (kbase ^ sw)); \
    bR[qn][nf][1] = *(const bf16x8*)(p + ((kbase + 64) ^ sw)); \
  } } while (0)

#define MMQ(qm, qn) do { \
  _Pragma("unroll") for (int mf = 0; mf < 4; ++mf) \
  _Pragma("unroll") for (int nf = 0; nf < 2; ++nf) { \
    acc[(qm)*4+mf][(qn)*2+nf] = __builtin_amdgcn_mfma_f32_16x16x32_bf16( \
        aR[mf][0], bR[qn][nf][0], acc[(qm)*4+mf][(qn)*2+nf], 0, 0, 0); \
    acc[(qm)*4+mf][(qn)*2+nf] = __builtin_amdgcn_mfma_f32_16x16x32_bf16( \
        aR[mf][1], bR[qn][nf][1], acc[(qm)*4+mf][(qn)*2+nf], 0, 0, 0); \
  } } while (0)

#define BAR()     __builtin_amdgcn_s_barrier()
#define PRIO1()   __builtin_amdgcn_s_setprio(1)
#define PRIO0()   __builtin_amdgcn_s_setprio(0)
#define VMCNT4()  asm volatile("s_waitcnt vmcnt(4)" ::: "memory")
#define LGKM8()   asm volatile("s_waitcnt lgkmcnt(8)" ::: "memory")
#define LGKM0_SB() do { asm volatile("s_waitcnt lgkmcnt(0)" ::: "memory"); \
                        __builtin_amdgcn_sched_barrier(0); } while (0)

  stageA(0, 0, 0); stageA(0, 1, 0); stageB(0, 0, 0); stageB(0, 1, 0);
  stageB(1, 0, 1); stageB(1, 1, 1);
  VMCNT4();
  BAR();

  for (int i = 0; i < NKT / 2; ++i) {
    const int t = 2 * i;
    LDA_Q(0, 0); LDB_Q(0, 0);
    stageA(1, 0, t + 1);
    LGKM8();
    BAR(); LGKM0_SB(); PRIO1(); MMQ(0, 0); PRIO0(); BAR();
    LDB_Q(0, 1);
    stageA(1, 1, t + 1);
    BAR(); LGKM0_SB(); PRIO1(); MMQ(0, 1); PRIO0(); BAR();
    LDA_Q(0, 1);
    stageB(0, 0, t + 2);
    BAR(); LGKM0_SB(); PRIO1(); MMQ(1, 1); PRIO0(); BAR();
    stageB(0, 1, t + 2);
    VMCNT4();
    BAR(); PRIO1(); MMQ(1, 0); PRIO0(); BAR();
    LDA_Q(1, 0); LDB_Q(1, 0);
    stageA(0, 0, t + 2);
    LGKM8();
    BAR(); LGKM0_SB(); PRIO1(); MMQ(0, 0); PRIO0(); BAR();
    LDB_Q(1, 1);
    stageA(0, 1, t + 2);
    BAR(); LGKM0_SB(); PRIO1(); MMQ(0, 1); PRIO0(); BAR();
    LDA_Q(1, 1);
    stageB(1, 0, t + 3);
    BAR(); LGKM0_SB(); PRIO1(); MMQ(1, 1); PRIO0(); BAR();
    stageB(1, 1, t + 3);
    VMCNT4();
    BAR(); PRIO1(); MMQ(1, 0); PRIO0(); BAR();
  }

  const int colL = colBase + wc * 64 + (lane & 15);
  float cn[4];
#pragma unroll
  for (int ni = 0; ni < 4; ++ni) cn[ni] = 0.5f * cnb[colL + ni * 16];
  const int nchunk = N >> 6;
  const int chunk  = (colBase >> 6) + wc;
#pragma unroll
  for (int mi = 0; mi < 8; ++mi) {
#pragma unroll
    for (int reg = 0; reg < 4; ++reg) {
      float best = acc[mi][0][reg] - cn[0];
      int   bc   = colL;
#pragma unroll
      for (int ni = 1; ni < 4; ++ni) {
        float v  = acc[mi][ni][reg] - cn[ni];
        int   c2 = colL + ni * 16;
        if (v > best || (v == best && c2 < bc)) { best = v; bc = c2; }
      }
#pragma unroll
      for (int m = 1; m < 16; m <<= 1) {
        float vo = __shfl_xor(best, m, 64);
        int   co = __shfl_xor(bc,   m, 64);
        if (vo > best || (vo == best && co < bc)) { best = vo; bc = co; }
      }
      if ((lane & 15) == 0) {
        int row = rowBase + wr * 128 + (mi >> 2) * 64 + (mi & 3) * 16
                + ((lane >> 4) << 2) + reg;
        if (row < M) {
          pval[(size_t)row * nchunk + chunk] = best;
          pidx[(size_t)row * nchunk + chunk] = bc;
        }
      }
    }
  }
#undef LDA_Q
#undef LDB_Q
#undef MMQ
#undef BAR
#undef PRIO1
#undef PRIO0
#undef VMCNT4
#undef LGKM8
#undef LGKM0_SB
}

// ------------------------------------------- candidate selection (per row)

__global__ __launch_bounds__(256) void cand_select(
    const float* __restrict__ pval1, int* __restrict__ lists,
    int* __restrict__ cnt)
{
  int row  = blockIdx.x * 4 + (threadIdx.x >> 6);
  int lane = threadIdx.x & 63;          // lane == chunk id (64 chunks)
  float v = pval1[(size_t)row * 64 + lane];
  float m = v;
#pragma unroll
  for (int s = 1; s < 64; s <<= 1) m = fmaxf(m, __shfl_xor(m, s, 64));
  if (v >= m - 1.0f) {                  // margin 2B = 1.0 (B=0.5, ~12 sigma)
    int pos = atomicAdd(&cnt[lane], 1);
    if (pos < LIST_CAP) lists[lane * LIST_CAP + pos] = row;
  }
}

// ---------------------------------- exact 3-term rescan of candidate chunks
// Gathered-row GEMM: 128 rows x 64 cols (one chunk) x K=3*1024 segments
// (x_hi.c_hi + x_lo.c_hi + x_hi.c_lo), identical math/order to the round-3
// score GEMM => scores bit-identical. Per-row chunk max -> pval2/pidx2.

template<int KK>
__global__ __launch_bounds__(256) void rescan(
    const u16* __restrict__ xhi, const u16* __restrict__ xlo,
    const u16* __restrict__ chi, const u16* __restrict__ clo,
    const float* __restrict__ cnorm,
    const int* __restrict__ lists, const int* __restrict__ cnt,
    float* __restrict__ pval2, int* __restrict__ pidx2)
{
  __shared__ char  smem[24576];         // A 16K [0,16K), B 8K [16K,24K)
  __shared__ int   rlist[128];
  __shared__ float sval[128];
  __shared__ int   sidx[128];

  const int chunk = blockIdx.x;
  const int n     = cnt[chunk];
  const int m0    = blockIdx.y * 128;
  if (m0 >= n) return;                  // uniform exit

  const int tid  = threadIdx.x;
  const int lane = tid & 63;
  const int wid  = tid >> 6;            // 0..3
  const int wm   = wid >> 1, wn = wid & 1;

  if (tid < 128) {
    int m = m0 + tid;
    rlist[tid] = lists[chunk * LIST_CAP + (m < n ? m : n - 1)];
  }
  __syncthreads();

  const int kswz = ((lane & 7) ^ (lane >> 3)) << 4;
  size_t aoff[4];
#pragma unroll
  for (int j = 0; j < 4; ++j) {
    int r = (wid * 4 + j) * 8 + (lane >> 3);
    aoff[j] = (size_t)rlist[r] * KK * 2 + kswz;
  }
  size_t boff[2];
#pragma unroll
  for (int j = 0; j < 2; ++j) {
    int r = (wid * 2 + j) * 8 + (lane >> 3);
    boff[j] = (size_t)(chunk * 64 + r) * KK * 2 + kswz;
  }

  const f32x4 zero4 = {0.f, 0.f, 0.f, 0.f};
  f32x4 acc[4][2];
#pragma unroll
  for (int i = 0; i < 4; ++i) { acc[i][0] = zero4; acc[i][1] = zero4; }

  for (int kt = 0; kt < 3 * (KK / 64); ++kt) {
    int seg = kt / (KK / 64);
    int k0b = (kt % (KK / 64)) << 7;    // (k0 elements)*2 bytes
    const char* Asrc = (const char*)(seg == 1 ? xlo : xhi) + k0b;
    const char* Bsrc = (const char*)(seg == 2 ? clo : chi) + k0b;
#pragma unroll
    for (int j = 0; j < 4; ++j)
      __builtin_amdgcn_global_load_lds((const AS1 void*)(Asrc + aoff[j]),
          (AS3 void*)(smem + (wid * 4 + j) * 1024), 16, 0, 0);
#pragma unroll
    for (int j = 0; j < 2; ++j)
      __builtin_amdgcn_global_load_lds((const AS1 void*)(Bsrc + boff[j]),
          (AS3 void*)(smem + 16384 + (wid * 2 + j) * 1024), 16, 0, 0);
    __syncthreads();
#pragma unroll
    for (int kk = 0; kk < 64; kk += 32) {
      bf16x8 a[4], b[2];
      const int kb = (kk + ((lane >> 4) << 3)) << 1;
#pragma unroll
      for (int mf = 0; mf < 4; ++mf) {
        int row = wm * 64 + mf * 16 + (lane & 15);
        a[mf] = *(const bf16x8*)(smem + row * 128 + (kb ^ ((row & 7) << 4)));
      }
#pragma unroll
      for (int nf = 0; nf < 2; ++nf) {
        int row = wn * 32 + nf * 16 + (lane & 15);
        b[nf] = *(const bf16x8*)(smem + 16384 + row * 128 + (kb ^ ((row & 7) << 4)));
      }
#pragma unroll
      for (int mf = 0; mf < 4; ++mf)
#pragma unroll
        for (int nf = 0; nf < 2; ++nf)
          acc[mf][nf] = __builtin_amdgcn_mfma_f32_16x16x32_bf16(
              a[mf], b[nf], acc[mf][nf], 0, 0, 0);
    }
    __syncthreads();
  }

  // epilogue: per-row best over this chunk's 64 cols (exact scores)
  const int colL = chunk * 64 + wn * 32 + (lane & 15);
  const float cn0 = 0.5f * cnorm[colL];
  const float cn1 = 0.5f * cnorm[colL + 16];
  float rbest[4][4]; int rbc[4][4];
#pragma unroll
  for (int mf = 0; mf < 4; ++mf)
#pragma unroll
    for (int reg = 0; reg < 4; ++reg) {
      float best = acc[mf][0][reg] - cn0;
      int   bc   = colL;
      float v1   = acc[mf][1][reg] - cn1;
      if (v1 > best || (v1 == best && colL + 16 < bc)) { best = v1; bc = colL + 16; }
#pragma unroll
      for (int m = 1; m < 16; m <<= 1) {
        float vo = __shfl_xor(best, m, 64);
        int   co = __shfl_xor(bc,   m, 64);
        if (vo > best || (vo == best && co < bc)) { best = vo; bc = co; }
      }
      rbest[mf][reg] = best; rbc[mf][reg] = bc;
    }
  if (wn == 1 && (lane & 15) == 0) {
#pragma unroll
    for (int mf = 0; mf < 4; ++mf)
#pragma unroll
      for (int reg = 0; reg < 4; ++reg) {
        int rloc = wm * 64 + mf * 16 + ((lane >> 4) << 2) + reg;
        sval[rloc] = rbest[mf][reg]; sidx[rloc] = rbc[mf][reg];
      }
  }
  __syncthreads();
  if (wn == 0 && (lane & 15) == 0) {
#pragma unroll
    for (int mf = 0; mf < 4; ++mf)
#pragma unroll
      for (int reg = 0; reg < 4; ++reg) {
        int rloc = wm * 64 + mf * 16 + ((lane >> 4) << 2) + reg;
        float best = rbest[mf][reg]; int bc = rbc[mf][reg];
        float vo = sval[rloc]; int co = sidx[rloc];
        if (vo > best || (vo == best && co < bc)) { best = vo; bc = co; }
        int row = rlist[rloc];
        pval2[(size_t)row * 64 + chunk] = best;
        pidx2[(size_t)row * 64 + chunk] = bc;
      }
  }
}

// -------------------------------------------------------------- small kernels

__global__ __launch_bounds__(256) void argmax_reduce(
    const float* __restrict__ pval, const int* __restrict__ pidx,
    int* __restrict__ idxOut, int nchunk)
{
  int row  = blockIdx.x * 4 + (threadIdx.x >> 6);
  int lane = threadIdx.x & 63;
  float v = pval[(size_t)row * nchunk + lane];
  int   c = pidx[(size_t)row * nchunk + lane];
#pragma unroll
  for (int m = 1; m < 64; m <<= 1) {
    float vo = __shfl_xor(v, m, 64);
    int   co = __shfl_xor(c, m, 64);
    if (vo > v || (vo == v && co < c)) { v = vo; c = co; }
  }
  if (lane == 0) idxOut[row] = c;
}

__global__ __launch_bounds__(256) void build_spk(
    const u16* __restrict__ xhi, const u16* __restrict__ xlo,
    const float* __restrict__ cent, const int* __restrict__ idx,
    u16* __restrict__ spk, int C)
{
  int row = blockIdx.x;
  const float* cr = cent + (size_t)idx[row] * C;
  size_t base = (size_t)row * C;
  for (int c = threadIdx.x; c < C; c += 256) {
    float v = b2f(xhi[base + c]) + b2f(xlo[base + c]) - cr[c];
    spk[base + c] = rne_bf16(v);
  }
}

__global__ __launch_bounds__(256) void transpose_out(
    const u16* __restrict__ spkdec, const float* __restrict__ cent,
    const int* __restrict__ idx, float* __restrict__ out, int C, int T)
{
  __shared__ float tile[64][65];
  int r0 = blockIdx.x * 64, c0 = blockIdx.y * 64;
#pragma unroll
  for (int i = 0; i < 16; ++i) {
    int id = threadIdx.x + i * 256;
    int lr = id >> 6, lc = id & 63;
    int row = r0 + lr;
    tile[lr][lc] = b2f(spkdec[(size_t)row * C + c0 + lc])
                 + cent[(size_t)idx[row] * C + c0 + lc];
  }
  __syncthreads();
#pragma unroll
  for (int i = 0; i < 16; ++i) {
    int id = threadIdx.x + i * 256;
    int lc = id >> 6, lr = id & 63;
    int row = r0 + lr;
    int b = row / T, t = row - b * T;
    out[((size_t)b * C + c0 + lc) * T + t] = tile[lr][lc];
  }
}

// ------------------------------------------------- 128^2 GEMM (MLP layers)

template<int NSEG, bool ACT>
__global__ __launch_bounds__(256) void gemm_bt(
    const u16* __restrict__ A0,
    const u16* __restrict__ B0,
    const float* __restrict__ cnb, u16* __restrict__ outb,
    int M, int N, int K)
{
  __shared__ bf16x8 smem8[2048];            // 32 KiB: A [0,16K), B [16K,32K)
  char* smem = (char*)smem8;

  const int lane = threadIdx.x & 63;
  const int wid  = threadIdx.x >> 6;
  const int wm   = wid >> 1, wn = wid & 1;

  const int rowBase = blockIdx.y * 128;
  const int colBase = blockIdx.x * 128;

  const f32x4 zero4 = {0.f, 0.f, 0.f, 0.f};
  f32x4 acc[4][4];
#pragma unroll
  for (int i = 0; i < 4; ++i)
#pragma unroll
    for (int j = 0; j < 4; ++j) acc[i][j] = zero4;

  const int l8   = lane >> 3;
  const int kbsw = ((lane & 7) ^ l8) << 4;
  const int nkt  = K >> 6;

  for (int kt = 0; kt < nkt; ++kt) {
    int k0 = kt << 6;
#pragma unroll
    for (int i = 0; i < 4; ++i) {
      int c = wid * 4 + i;
      int r = c * 8 + l8;
      int gra = rowBase + r; gra = gra < M ? gra : (M - 1);
      const char* ga = (const char*)A0 + ((size_t)gra * K + k0) * 2 + kbsw;
      __builtin_amdgcn_global_load_lds((const AS1 void*)ga,
                                       (AS3 void*)(smem + c * 1024), 16, 0, 0);
      int grb = colBase + r;
      const char* gb = (const char*)B0 + ((size_t)grb * K + k0) * 2 + kbsw;
      __builtin_amdgcn_global_load_lds((const AS1 void*)gb,
                                       (AS3 void*)(smem + 16384 + c * 1024), 16, 0, 0);
    }
    __syncthreads();

#pragma unroll
    for (int kk = 0; kk < 64; kk += 32) {
      bf16x8 a[4], b[4];
      const int kb = (kk + ((lane >> 4) << 3)) << 1;
#pragma unroll
      for (int mf = 0; mf < 4; ++mf) {
        int row = wm * 64 + mf * 16 + (lane & 15);
        a[mf] = *(const bf16x8*)(smem + row * 128 + (kb ^ ((row & 7) << 4)));
      }
#pragma unroll
      for (int nf = 0; nf < 4; ++nf) {
        int row = wn * 64 + nf * 16 + (lane & 15);
        b[nf] = *(const bf16x8*)(smem + 16384 + row * 128 + (kb ^ ((row & 7) << 4)));
      }
#pragma unroll
      for (int mf = 0; mf < 4; ++mf)
#pragma unroll
        for (int nf = 0; nf < 4; ++nf)
          acc[mf][nf] = __builtin_amdgcn_mfma_f32_16x16x32_bf16(
              a[mf], b[nf], acc[mf][nf], 0, 0, 0);
    }
    __syncthreads();
  }

  const int colLane = colBase + wn * 64 + (lane & 15);
  float bl[4];
#pragma unroll
  for (int nf = 0; nf < 4; ++nf) bl[nf] = cnb[colLane + nf * 16];
#pragma unroll
  for (int mf = 0; mf < 4; ++mf)
#pragma unroll
    for (int nf = 0; nf < 4; ++nf)
#pragma unroll
      for (int reg = 0; reg < 4; ++reg) {
        int row = rowBase + wm * 64 + mf * 16 + ((lane >> 4) << 2) + reg;
        if (row < M) {
          float v = acc[mf][nf][reg] + bl[nf];
          if (ACT) v = v > 0.f ? v : 0.01f * v;
          outb[(size_t)row * N + colLane + nf * 16] = rne_bf16(v);
        }
      }
}

// --------------------------------------------------------------------- launch

extern "C" void kernel_launch(void* const* d_in, const int* in_sizes, int n_in,
                              void* d_out, int out_size, void* d_ws, size_t ws_size,
                              hipStream_t stream)
{
  const float* feature  = (const float*)d_in[0];
  const float* centroid = (const float*)d_in[1];
  const float* ew0 = (const float*)d_in[2];
  const float* eb0 = (const float*)d_in[3];
  const float* ew1 = (const float*)d_in[4];
  const float* eb1 = (const float*)d_in[5];
  const float* ew2 = (const float*)d_in[6];
  const float* eb2 = (const float*)d_in[7];
  const float* dw0 = (const float*)d_in[8];
  const float* db0 = (const float*)d_in[9];
  const float* dw1 = (const float*)d_in[10];
  const float* db1 = (const float*)d_in[11];
  const float* dw2 = (const float*)d_in[12];
  const float* db2 = (const float*)d_in[13];
  float* out = (float*)d_out;

  const int Bb = 16, C = 1024, T = 1500, M = Bb * T;    // M = 24000
  const int NBIN = 4096, HID = 512, EMB = 256;
  const int MB  = (M + 127) / 128;                      // 188
  const int MB2 = (M + 255) / 256;                      // 94

  char* ws = (char*)d_ws;
  size_t off = 0;
  auto alloc = [&](size_t bytes) -> char* {
    char* p = ws + off;
    off += (bytes + 255) & ~(size_t)255;
    return p;
  };
  u16*   c_hi  = (u16*)  alloc((size_t)NBIN * C * 2);
  u16*   c_lo  = (u16*)  alloc((size_t)NBIN * C * 2);
  float* cnorm = (float*)alloc((size_t)NBIN * 4);
  u16*   wb0   = (u16*)  alloc((size_t)HID * C   * 2);
  u16*   wb1   = (u16*)  alloc((size_t)HID * HID * 2);
  u16*   wb2   = (u16*)  alloc((size_t)EMB * HID * 2);
  u16*   wb3   = (u16*)  alloc((size_t)HID * EMB * 2);
  u16*   wb4   = (u16*)  alloc((size_t)HID * HID * 2);
  u16*   wb5   = (u16*)  alloc((size_t)C   * HID * 2);
  u16*   x_hi  = (u16*)  alloc((size_t)M * C * 2);
  u16*   x_lo  = (u16*)  alloc((size_t)M * C * 2);
  int*   idx   = (int*)  alloc((size_t)M * 4);
  char*  spkR  =         alloc((size_t)M * C * 2);      // spk, later spk_dec
  u16*   spk   = (u16*)spkR;
  float* pval1 = (float*)spkR;                          // overlay (pre-spk)
  int*   pidx1 = (int*)(spkR + (size_t)M * 64 * 4);     // overlay (pre-spk)
  u16*   h1    = (u16*)  alloc((size_t)M * HID * 2);
  u16*   h2    = (u16*)  alloc((size_t)M * HID * 2);
  u16*   hz    = (u16*)  alloc((size_t)M * EMB * 2);
  float* pval2 = (float*)h1;                            // overlay (pre-MLP) 6.1 MB
  int*   pidx2 = (int*)h2;                              // overlay (pre-MLP) 6.1 MB
  int*   lists = (int*)hz;                              // overlay (pre-MLP) 512 KB
  int*   cnt   = (int*)(hz + (size_t)64 * LIST_CAP * 2); // (hz is u16*, +1MB bytes)

  // conversions
  conv_centroid<<<NBIN / 4, 256, 0, stream>>>(centroid, c_hi, c_lo, cnorm, C);
  conv_feature<<<dim3((T + 63) / 64, C / 64, Bb), 256, 0, stream>>>(feature, x_hi, x_lo, C, T);
  f2bf<<<(HID * C   + 255) / 256, 256, 0, stream>>>(ew0, wb0, HID * C);
  f2bf<<<(HID * HID + 255) / 256, 256, 0, stream>>>(ew1, wb1, HID * HID);
  f2bf<<<(EMB * HID + 255) / 256, 256, 0, stream>>>(ew2, wb2, EMB * HID);
  f2bf<<<(HID * EMB + 255) / 256, 256, 0, stream>>>(dw0, wb3, HID * EMB);
  f2bf<<<(HID * HID + 255) / 256, 256, 0, stream>>>(dw1, wb4, HID * HID);
  f2bf<<<(C   * HID + 255) / 256, 256, 0, stream>>>(dw2, wb5, C * HID);

  // init two-pass scratch
  hipMemsetAsync(cnt, 0, 64 * sizeof(int), stream);
  hipMemsetAsync(pval2, 0xFE, (size_t)M * 64 * 4, stream);   // ~ -1.7e38

  // pass 1: 1-term approx scores with fused per-chunk argmax
  score256<1024, 1><<<dim3(NBIN / 256, MB2), 512, 0, stream>>>(
      x_hi, x_hi, x_hi, c_hi, c_hi, c_hi, cnorm, pval1, pidx1, M, NBIN);

  // candidate chunks + exact rescan + final argmax
  cand_select<<<M / 4, 256, 0, stream>>>(pval1, lists, cnt);
  rescan<1024><<<dim3(64, LIST_CAP / 128), 256, 0, stream>>>(
      x_hi, x_lo, c_hi, c_lo, cnorm, lists, cnt, pval2, pidx2);
  argmax_reduce<<<M / 4, 256, 0, stream>>>(pval2, pidx2, idx, 64);

  build_spk<<<M, 256, 0, stream>>>(x_hi, x_lo, centroid, idx, spk, C);

  // MLP encoder/decoder
  gemm_bt<1, true ><<<dim3(HID / 128, MB), 256, 0, stream>>>(spk, wb0, eb0, h1, M, HID, C);
  gemm_bt<1, true ><<<dim3(HID / 128, MB), 256, 0, stream>>>(h1, wb1, eb1, h2, M, HID, HID);
  gemm_bt<1, false><<<dim3(EMB / 128, MB), 256, 0, stream>>>(h2, wb2, eb2, (u16*)hz, M, EMB, HID);
  gemm_bt<1, true ><<<dim3(HID / 128, MB), 256, 0, stream>>>((u16*)hz, wb3, db0, h1, M, HID, EMB);
  gemm_bt<1, true ><<<dim3(HID / 128, MB), 256, 0, stream>>>(h1, wb4, db1, h2, M, HID, HID);
  gemm_bt<1, false><<<dim3(C / 128, MB), 256, 0, stream>>>(h2, wb5, db2, spk, M, C, HID);

  transpose_out<<<dim3(M / 64, C / 64), 256, 0, stream>>>(spk, centroid, idx, out, C, T);
}